// Round 1
// baseline (5116.357 us; speedup 1.0000x reference)
//
#include <hip/hip_runtime.h>
#include <stdint.h>

// SoftNMS (gaussian, sigma=0.5, thr=0.001), N=4096, 2 classes.
// R7: EXACT BATCHED SELECTION. R1-R6 showed the ~5500-cycle per-iteration cost
// is structural (invariant to VALU/barriers/stores/clock). Decay factors are
// geometry-only, so a pairwise-disjoint prefix of the key order can be
// committed per iteration, bit-identically. Visibility guard:
//   G = max( block-max of per-thread 2nd key, wave-max of per-column 2nd key )
// guarantees every live key > G is among the 64 column maxima that wave 0
// sorts. Batch = sorted prefix while (key > G) && pairwise inter==0 && < 16.
// Decays applied in batch order with the byte-identical FP body of the
// verified serial kernel. Expected ~8-12 selections/iteration -> ~240
// iterations/class instead of ~2048. Fillers dropped (R6: proven neutral).

#define N_BOXES 4096
#define T 256
#define CAP 16            // slots/thread capacity (worst case: one class owns all)
#define BOXCAP 2560       // LDS cache capacity (40KB box + 20KB key)
#define SCORE_THR 0.001f
#define BATCH_MAX 16

typedef unsigned long long u64;
typedef uint32_t u32;

__device__ __forceinline__ u64 kmax(u64 a, u64 b) { return a > b ? a : b; }
__device__ __forceinline__ u64 kmin(u64 a, u64 b) { return a < b ? a : b; }

// LLVM gfx9 wave64 reduction sequence; identity 0, inputs non-negative.
__device__ __forceinline__ int wave_max_nonneg(int v) {
    v = max(v, __builtin_amdgcn_update_dpp(0, v, 0x111, 0xf, 0xf, false)); // row_shr:1
    v = max(v, __builtin_amdgcn_update_dpp(0, v, 0x112, 0xf, 0xf, false)); // row_shr:2
    v = max(v, __builtin_amdgcn_update_dpp(0, v, 0x114, 0xf, 0xf, false)); // row_shr:4
    v = max(v, __builtin_amdgcn_update_dpp(0, v, 0x118, 0xf, 0xf, false)); // row_shr:8
    v = max(v, __builtin_amdgcn_update_dpp(0, v, 0x142, 0xa, 0xf, false)); // row_bcast:15
    v = max(v, __builtin_amdgcn_update_dpp(0, v, 0x143, 0xc, 0xf, false)); // row_bcast:31
    return __builtin_amdgcn_readlane(v, 63);
}

// exact u64 wave max, two-phase (score bits then tie-break bits); both halves
// are non-negative as ints by construction of the key.
__device__ __forceinline__ u64 wave_max_u64(u64 x) {
    int hi   = (int)(u32)(x >> 32);
    int hmax = wave_max_nonneg(hi);
    int lom  = (hi == hmax) ? (int)(u32)x : 0;
    int lmax = wave_max_nonneg(lom);
    return ((u64)(u32)hmax << 32) | (u64)(u32)lmax;
}

__device__ __forceinline__ u64 shflxor64(u64 v, int m) {
    int lo = __shfl_xor((int)(u32)(v & 0xFFFFFFFFull), m, 64);
    int hi = __shfl_xor((int)(u32)(v >> 32), m, 64);
    return ((u64)(u32)hi << 32) | (u64)(u32)lo;
}

// workspace layout (196624 bytes)
#define WS_KEY(ws, c)  ((u64*)((char*)(ws) + (size_t)(c) * 32768))
#define WS_BOX(ws, c)  ((float4*)((char*)(ws) + 65536 + (size_t)(c) * 65536))
#define WS_CNT(ws)     ((int*)((char*)(ws) + 196608))

__launch_bounds__(T, 1)
__global__ void softnms_fused(const float* __restrict__ boxes,
                              const float* __restrict__ scores,
                              const int* __restrict__ labels,
                              void* __restrict__ ws) {
    const int cls  = blockIdx.x;
    const int tid  = threadIdx.x;
    const int lane = tid & 63;
    const int wid  = tid >> 6;

    __shared__ u64    maskw[64];          // class-membership bitmask
    __shared__ u32    wordpref[64];       // inclusive prefix of popcounts
    __shared__ u64    redG[4];            // per-wave max of per-thread 2nd key
    __shared__ u64    cand[2 * T];        // per-thread top-2 posting (512)
    __shared__ float4 candbox[BATCH_MAX - 1];
    __shared__ u64    batchkey[BATCH_MAX];
    __shared__ float4 batchbox[BATCH_MAX];
    __shared__ int    nbatchS;
    __shared__ float4 box_lds[BOXCAP];
    __shared__ u64    okey_lds[BOXCAP];

    // ---- phase 0a: membership bitmask + popcount prefix ----
    for (int base = 0; base < N_BOXES; base += T) {
        u64 bal = __ballot(labels[base + tid] == cls);
        if (lane == 0) maskw[(base >> 6) + wid] = bal;
    }
    __syncthreads();
    if (wid == 0) {
        u32 v = (u32)__popcll(maskw[lane]);
        #pragma unroll
        for (int d = 1; d < 64; d <<= 1) {
            u32 o = __shfl_up(v, d, 64);
            if (lane >= d) v += o;
        }
        wordpref[lane] = v;
    }
    __syncthreads();
    const int cnt = (int)wordpref[63];

    // ---- phase 0b: rank-select my slots (r = tid + 256*j) -> regs + LDS ----
    float x1r[CAP], y1r[CAP], x2r[CAP], y2r[CAP], ar[CAP];
    u64 key[CAP];
    const float4* boxes4 = reinterpret_cast<const float4*>(boxes);
    #pragma unroll
    for (int j = 0; j < CAP; ++j) {
        key[j] = 0;
        x1r[j] = 0.0f; y1r[j] = 0.0f; x2r[j] = 0.0f; y2r[j] = 0.0f; ar[j] = 0.0f;
        int r = tid + T * j;
        if (r < cnt) {
            int lo = 0, hi = 63;   // smallest word W with wordpref[W] > r
            while (lo < hi) { int mid = (lo + hi) >> 1; if (wordpref[mid] > (u32)r) hi = mid; else lo = mid + 1; }
            int W = lo;
            u32 rb = (W == 0) ? 0u : wordpref[W - 1];
            u32 t = (u32)r - rb;
            u64 x = maskw[W];
            int pos = 0;
            u32 c;
            c = (u32)__popcll(x & 0xFFFFFFFFull); if (t >= c) { pos += 32; t -= c; x >>= 32; }
            c = (u32)__popcll(x & 0xFFFFull);     if (t >= c) { pos += 16; t -= c; x >>= 16; }
            c = (u32)__popcll(x & 0xFFull);       if (t >= c) { pos += 8;  t -= c; x >>= 8; }
            c = (u32)__popcll(x & 0xFull);        if (t >= c) { pos += 4;  t -= c; x >>= 4; }
            c = (u32)__popcll(x & 0x3ull);        if (t >= c) { pos += 2;  t -= c; x >>= 2; }
            c = (u32)__popcll(x & 0x1ull);        if (t >= c) { pos += 1; }
            int g = W * 64 + pos;
            float4 b = boxes4[g];
            x1r[j] = b.x; y1r[j] = b.y; x2r[j] = b.z; y2r[j] = b.w;
            ar[j]  = __fmul_rn(__fsub_rn(b.z, b.x), __fsub_rn(b.w, b.y));
            float s = scores[g];
            // key: score<<32 | (4095-g)<<16 | r   (g: argmax tie-break; r: slot)
            key[j] = ((u64)__float_as_uint(s) << 32)
                   | ((u64)(u32)(4095 - g) << 16) | (u64)(u32)r;
            if (r < BOXCAP) box_lds[r] = b;
        }
    }
    __syncthreads();

    // ---- phase 1: batched soft-NMS over this class ----
    u64*    okey = WS_KEY(ws, cls);
    float4* obox = WS_BOX(ws, cls);
    const bool use_lds = (cnt <= BOXCAP);
    int mcnt = 0;

    for (;;) {
        // per-thread top-2 of live keys (branchless)
        u64 m1 = 0, m2 = 0;
        #pragma unroll
        for (int j = 0; j < CAP; ++j) {
            u64 kj  = key[j];
            u64 nm1 = kmax(m1, kj);
            m2 = kmax(m2, kmin(m1, kj));
            m1 = nm1;
        }
        // thread-hiding guard: block max of per-thread 2nd keys
        u64 wg = wave_max_u64(m2);
        if (lane == 0) redG[wid] = wg;
        cand[2 * tid]     = m1;
        cand[2 * tid + 1] = m2;
        __syncthreads();                               // B_a

        if (tid < 64) {
            // column top-2 over cand[lane + 64*e]
            u64 a1 = 0, a2 = 0;
            #pragma unroll
            for (int e = 0; e < 8; ++e) {
                u64 c   = cand[lane + 64 * e];
                u64 na1 = kmax(a1, c);
                a2 = kmax(a2, kmin(a1, c));
                a1 = na1;
            }
            // visibility guard: every live key > G is some column's a1
            u64 G = kmax(kmax(redG[0], redG[1]), kmax(redG[2], redG[3]));
            G = kmax(G, wave_max_u64(a2));

            // bitonic sort the 64 column maxima, descending (zeros sink)
            u64 v = a1;
            #pragma unroll
            for (int kk = 2; kk <= 64; kk <<= 1) {
                #pragma unroll
                for (int jj = kk >> 1; jj > 0; jj >>= 1) {
                    u64 o = shflxor64(v, jj);
                    bool up    = (lane & kk) != 0;
                    bool lower = (lane & jj) == 0;
                    u64 mn = kmin(v, o), mx = kmax(v, o);
                    v = (lower == up) ? mn : mx;
                }
            }
            u64 ki = v;
            int r  = (int)(ki & 0xFFFF);
            float4 bi;
            if (use_lds) bi = box_lds[r];
            else         bi = boxes4[4095 - (int)((ki >> 16) & 0xFFFF)];
            if (lane < BATCH_MAX - 1) candbox[lane] = bi;
            __threadfence_block();
            // conflict with any earlier candidate (selected => prefix rule)
            bool conflict = false;
            #pragma unroll
            for (int j2 = 0; j2 < BATCH_MAX - 1; ++j2) {
                if (j2 < lane) {
                    float4 bj = candbox[j2];
                    float ix1 = fmaxf(bj.x, bi.x);
                    float iy1 = fmaxf(bj.y, bi.y);
                    float ix2 = fminf(bj.z, bi.z);
                    float iy2 = fminf(bj.w, bi.w);
                    float iw  = fmaxf(__fsub_rn(ix2, ix1), 0.0f);
                    float ih  = fmaxf(__fsub_rn(iy2, iy1), 0.0f);
                    conflict |= (__fmul_rn(iw, ih) > 0.0f);
                }
            }
            bool stop = (ki <= G) || (lane >= BATCH_MAX) || conflict;
            u64 bal = __ballot(stop);                  // lanes>=16 always stop
            int k = __builtin_ctzll(bal);              // k in [0,16]
            if (lane < k) {
                batchkey[lane] = ki;
                batchbox[lane] = bi;
                if (use_lds) okey_lds[mcnt + lane] = ki;
                else { okey[mcnt + lane] = ki; obox[mcnt + lane] = bi; }
            }
            if (lane == 0) nbatchS = k;
        }
        __syncthreads();                               // B_b

        int k = nbatchS;
        if (k == 0) break;                             // all suppressed/selected
        mcnt += k;

        // apply the k decays IN SELECTION ORDER (byte-identical serial body)
        for (int b = 0; b < k; ++b) {
            u64    kb = batchkey[b];
            float4 wb = batchbox[b];
            float wx1 = wb.x, wy1 = wb.y, wx2 = wb.z, wy2 = wb.w;
            float warea = __fmul_rn(__fsub_rn(wx2, wx1), __fsub_rn(wy2, wy1));
            #pragma unroll
            for (int j = 0; j < CAP; ++j) {
                u64 kj = key[j];
                if (kj != 0) {
                    if (kj == kb) {
                        key[j] = 0;
                    } else {
                        float ix1   = fmaxf(wx1, x1r[j]);
                        float iy1   = fmaxf(wy1, y1r[j]);
                        float ix2   = fminf(wx2, x2r[j]);
                        float iy2   = fminf(wy2, y2r[j]);
                        float iw    = fmaxf(__fsub_rn(ix2, ix1), 0.0f);
                        float ih    = fmaxf(__fsub_rn(iy2, iy1), 0.0f);
                        float inter = __fmul_rn(iw, ih);
                        if (inter > 0.0f) {
                            float sc    = __uint_as_float((u32)(kj >> 32));
                            float denom = __fadd_rn(__fsub_rn(__fadd_rn(warea, ar[j]), inter), 1e-8f);
                            float iou   = inter / denom;                // IEEE div
                            float t2    = __fmul_rn(iou, iou);
                            float decay = expf(__fmul_rn(-2.0f, t2));   // exp(-iou^2/0.5)
                            float ns    = __fmul_rn(sc, decay);
                            key[j] = (ns >= SCORE_THR)
                                       ? (((u64)__float_as_uint(ns) << 32) | (kj & 0xFFFFFFFFull))
                                       : 0;
                        }
                    }
                }
            }
        }
    }

    // ---- batched flush of staged winners (boxes recovered by rank) ----
    if (use_lds) {
        __syncthreads();
        for (int m = tid; m < mcnt; m += T) {
            u64 w = okey_lds[m];
            okey[m] = w;
            obox[m] = box_lds[(int)(w & 0xFFFF)];
        }
    }
    if (tid == 0) WS_CNT(ws)[cls] = mcnt;
}

// merge the two strictly-descending key lists by rank; pad the tail
__global__ void softnms_merge(void* __restrict__ ws, float* __restrict__ out) {
    int k = blockIdx.x * blockDim.x + threadIdx.x;   // 0..4095
    const u64*    keyA = WS_KEY(ws, 0);
    const u64*    keyB = WS_KEY(ws, 1);
    const float4* boxA = WS_BOX(ws, 0);
    const float4* boxB = WS_BOX(ws, 1);
    const int mA = WS_CNT(ws)[0];
    const int mB = WS_CNT(ws)[1];

    float* ob = out;
    float* os = out + N_BOXES * 4;
    float* ol = out + N_BOXES * 5;

    if (k < mA) {
        u64 x = keyA[k];
        int lo = 0, hi = mB;
        while (lo < hi) { int mid = (lo + hi) >> 1; if (keyB[mid] > x) lo = mid + 1; else hi = mid; }
        int pos = k + lo;
        float4 b = boxA[k];
        ob[pos * 4 + 0] = b.x; ob[pos * 4 + 1] = b.y;
        ob[pos * 4 + 2] = b.z; ob[pos * 4 + 3] = b.w;
        os[pos] = __uint_as_float((u32)(x >> 32));
        ol[pos] = 0.0f;
    } else if (k < mA + mB) {
        int i = k - mA;
        u64 x = keyB[i];
        int lo = 0, hi = mA;
        while (lo < hi) { int mid = (lo + hi) >> 1; if (keyA[mid] > x) lo = mid + 1; else hi = mid; }
        int pos = i + lo;
        float4 b = boxB[i];
        ob[pos * 4 + 0] = b.x; ob[pos * 4 + 1] = b.y;
        ob[pos * 4 + 2] = b.z; ob[pos * 4 + 3] = b.w;
        os[pos] = __uint_as_float((u32)(x >> 32));
        ol[pos] = 1.0f;
    } else {
        ob[k * 4 + 0] = 0.0f; ob[k * 4 + 1] = 0.0f;
        ob[k * 4 + 2] = 0.0f; ob[k * 4 + 3] = 0.0f;
        os[k] = 0.0f;
        ol[k] = -1.0f;
    }
}

extern "C" void kernel_launch(void* const* d_in, const int* in_sizes, int n_in,
                              void* d_out, int out_size, void* d_ws, size_t ws_size,
                              hipStream_t stream) {
    const float* boxes  = (const float*)d_in[0];
    const float* scores = (const float*)d_in[1];
    const int*   labels = (const int*)d_in[2];
    float* out = (float*)d_out;
    (void)in_sizes; (void)n_in; (void)out_size; (void)ws_size;
    softnms_fused<<<2, T, 0, stream>>>(boxes, scores, labels, d_ws);
    softnms_merge<<<N_BOXES / 256, 256, 0, stream>>>(d_ws, out);
}

// Round 2
// 4369.072 us; speedup vs baseline: 1.1710x; 1.1710x over previous
//
#include <hip/hip_runtime.h>
#include <stdint.h>

// SoftNMS (gaussian, sigma=0.5, thr=0.001), N=4096, 2 classes.
// R8: BRANCHLESS FUSED DECAY. R7 (exact batched selection) was time-neutral:
// total = 2048 x D + iters x overhead, with D ~ 2.2us = one decay pass. D is
// exposed-latency-bound: each slot's `if(inter>0){div;exp;}` is its own
// exec-mask region; chains can't interleave at 1 wave/SIMD. This round keeps
// the R7 selection machinery bit-identical and rewrites ONLY the decay:
// b-outer / slot-inner fully unrolled, per-lane branchless (div+exp always,
// commit via selects; expf(-0.0)=1.0 exactly so inter==0 is a bitwise no-op),
// slot loop bounded by wave-uniform jmax. Serial mul order + kill rule kept
// => bit-exact. Expect decay ~640cyc/selection instead of ~5300.

#define N_BOXES 4096
#define T 256
#define CAP 16            // slots/thread capacity (worst case: one class owns all)
#define BOXCAP 2560       // LDS cache capacity (40KB box + 20KB key)
#define SCORE_THR 0.001f
#define BATCH_MAX 16

typedef unsigned long long u64;
typedef uint32_t u32;

__device__ __forceinline__ u64 kmax(u64 a, u64 b) { return a > b ? a : b; }
__device__ __forceinline__ u64 kmin(u64 a, u64 b) { return a < b ? a : b; }

// LLVM gfx9 wave64 reduction sequence; identity 0, inputs non-negative.
__device__ __forceinline__ int wave_max_nonneg(int v) {
    v = max(v, __builtin_amdgcn_update_dpp(0, v, 0x111, 0xf, 0xf, false)); // row_shr:1
    v = max(v, __builtin_amdgcn_update_dpp(0, v, 0x112, 0xf, 0xf, false)); // row_shr:2
    v = max(v, __builtin_amdgcn_update_dpp(0, v, 0x114, 0xf, 0xf, false)); // row_shr:4
    v = max(v, __builtin_amdgcn_update_dpp(0, v, 0x118, 0xf, 0xf, false)); // row_shr:8
    v = max(v, __builtin_amdgcn_update_dpp(0, v, 0x142, 0xa, 0xf, false)); // row_bcast:15
    v = max(v, __builtin_amdgcn_update_dpp(0, v, 0x143, 0xc, 0xf, false)); // row_bcast:31
    return __builtin_amdgcn_readlane(v, 63);
}

// exact u64 wave max, two-phase (score bits then tie-break bits); both halves
// are non-negative as ints by construction of the key.
__device__ __forceinline__ u64 wave_max_u64(u64 x) {
    int hi   = (int)(u32)(x >> 32);
    int hmax = wave_max_nonneg(hi);
    int lom  = (hi == hmax) ? (int)(u32)x : 0;
    int lmax = wave_max_nonneg(lom);
    return ((u64)(u32)hmax << 32) | (u64)(u32)lmax;
}

__device__ __forceinline__ u64 shflxor64(u64 v, int m) {
    int lo = __shfl_xor((int)(u32)(v & 0xFFFFFFFFull), m, 64);
    int hi = __shfl_xor((int)(u32)(v >> 32), m, 64);
    return ((u64)(u32)hi << 32) | (u64)(u32)lo;
}

// workspace layout (196624 bytes)
#define WS_KEY(ws, c)  ((u64*)((char*)(ws) + (size_t)(c) * 32768))
#define WS_BOX(ws, c)  ((float4*)((char*)(ws) + 65536 + (size_t)(c) * 65536))
#define WS_CNT(ws)     ((int*)((char*)(ws) + 196608))

__launch_bounds__(T, 1)
__global__ void softnms_fused(const float* __restrict__ boxes,
                              const float* __restrict__ scores,
                              const int* __restrict__ labels,
                              void* __restrict__ ws) {
    const int cls  = blockIdx.x;
    const int tid  = threadIdx.x;
    const int lane = tid & 63;
    const int wid  = tid >> 6;

    __shared__ u64    maskw[64];          // class-membership bitmask
    __shared__ u32    wordpref[64];       // inclusive prefix of popcounts
    __shared__ u64    redG[4];            // per-wave max of per-thread 2nd key
    __shared__ u64    cand[2 * T];        // per-thread top-2 posting (512)
    __shared__ float4 candbox[BATCH_MAX - 1];
    __shared__ u64    batchkey[BATCH_MAX];
    __shared__ float4 batchbox[BATCH_MAX];
    __shared__ int    nbatchS;
    __shared__ float4 box_lds[BOXCAP];
    __shared__ u64    okey_lds[BOXCAP];

    // ---- phase 0a: membership bitmask + popcount prefix ----
    for (int base = 0; base < N_BOXES; base += T) {
        u64 bal = __ballot(labels[base + tid] == cls);
        if (lane == 0) maskw[(base >> 6) + wid] = bal;
    }
    __syncthreads();
    if (wid == 0) {
        u32 v = (u32)__popcll(maskw[lane]);
        #pragma unroll
        for (int d = 1; d < 64; d <<= 1) {
            u32 o = __shfl_up(v, d, 64);
            if (lane >= d) v += o;
        }
        wordpref[lane] = v;
    }
    __syncthreads();
    const int cnt = __builtin_amdgcn_readfirstlane((int)wordpref[63]);

    // ---- phase 0b: rank-select my slots (r = tid + 256*j) -> regs + LDS ----
    float x1r[CAP], y1r[CAP], x2r[CAP], y2r[CAP], ar[CAP];
    u64 key[CAP];
    const float4* boxes4 = reinterpret_cast<const float4*>(boxes);
    #pragma unroll
    for (int j = 0; j < CAP; ++j) {
        key[j] = 0;
        x1r[j] = 0.0f; y1r[j] = 0.0f; x2r[j] = 0.0f; y2r[j] = 0.0f; ar[j] = 0.0f;
        int r = tid + T * j;
        if (r < cnt) {
            int lo = 0, hi = 63;   // smallest word W with wordpref[W] > r
            while (lo < hi) { int mid = (lo + hi) >> 1; if (wordpref[mid] > (u32)r) hi = mid; else lo = mid + 1; }
            int W = lo;
            u32 rb = (W == 0) ? 0u : wordpref[W - 1];
            u32 t = (u32)r - rb;
            u64 x = maskw[W];
            int pos = 0;
            u32 c;
            c = (u32)__popcll(x & 0xFFFFFFFFull); if (t >= c) { pos += 32; t -= c; x >>= 32; }
            c = (u32)__popcll(x & 0xFFFFull);     if (t >= c) { pos += 16; t -= c; x >>= 16; }
            c = (u32)__popcll(x & 0xFFull);       if (t >= c) { pos += 8;  t -= c; x >>= 8; }
            c = (u32)__popcll(x & 0xFull);        if (t >= c) { pos += 4;  t -= c; x >>= 4; }
            c = (u32)__popcll(x & 0x3ull);        if (t >= c) { pos += 2;  t -= c; x >>= 2; }
            c = (u32)__popcll(x & 0x1ull);        if (t >= c) { pos += 1; }
            int g = W * 64 + pos;
            float4 b = boxes4[g];
            x1r[j] = b.x; y1r[j] = b.y; x2r[j] = b.z; y2r[j] = b.w;
            ar[j]  = __fmul_rn(__fsub_rn(b.z, b.x), __fsub_rn(b.w, b.y));
            float s = scores[g];
            // key: score<<32 | (4095-g)<<16 | r   (g: argmax tie-break; r: slot)
            key[j] = ((u64)__float_as_uint(s) << 32)
                   | ((u64)(u32)(4095 - g) << 16) | (u64)(u32)r;
            if (r < BOXCAP) box_lds[r] = b;
        }
    }
    __syncthreads();

    // ---- phase 1: batched soft-NMS over this class ----
    u64*    okey = WS_KEY(ws, cls);
    float4* obox = WS_BOX(ws, cls);
    const bool use_lds = (cnt <= BOXCAP);
    int mcnt = 0;

    for (;;) {
        // per-thread top-2 of live keys (branchless; wave-uniform slot bound)
        u64 m1 = 0, m2 = 0;
        #pragma unroll
        for (int j = 0; j < CAP; ++j) {
            if (T * j < cnt) {
                u64 kj  = key[j];
                u64 nm1 = kmax(m1, kj);
                m2 = kmax(m2, kmin(m1, kj));
                m1 = nm1;
            }
        }
        // thread-hiding guard: block max of per-thread 2nd keys
        u64 wg = wave_max_u64(m2);
        if (lane == 0) redG[wid] = wg;
        cand[2 * tid]     = m1;
        cand[2 * tid + 1] = m2;
        __syncthreads();                               // B_a

        if (tid < 64) {
            // column top-2 over cand[lane + 64*e]
            u64 a1 = 0, a2 = 0;
            #pragma unroll
            for (int e = 0; e < 8; ++e) {
                u64 c   = cand[lane + 64 * e];
                u64 na1 = kmax(a1, c);
                a2 = kmax(a2, kmin(a1, c));
                a1 = na1;
            }
            // visibility guard: every live key > G is some column's a1
            u64 G = kmax(kmax(redG[0], redG[1]), kmax(redG[2], redG[3]));
            G = kmax(G, wave_max_u64(a2));

            // bitonic sort the 64 column maxima, descending (zeros sink)
            u64 v = a1;
            #pragma unroll
            for (int kk = 2; kk <= 64; kk <<= 1) {
                #pragma unroll
                for (int jj = kk >> 1; jj > 0; jj >>= 1) {
                    u64 o = shflxor64(v, jj);
                    bool up    = (lane & kk) != 0;
                    bool lower = (lane & jj) == 0;
                    u64 mn = kmin(v, o), mx = kmax(v, o);
                    v = (lower == up) ? mn : mx;
                }
            }
            u64 ki = v;
            int r  = (int)(ki & 0xFFFF);
            float4 bi;
            if (use_lds) bi = box_lds[r];
            else         bi = boxes4[4095 - (int)((ki >> 16) & 0xFFFF)];
            if (lane < BATCH_MAX - 1) candbox[lane] = bi;
            __threadfence_block();
            // conflict with any earlier candidate (selected => prefix rule)
            bool conflict = false;
            #pragma unroll
            for (int j2 = 0; j2 < BATCH_MAX - 1; ++j2) {
                if (j2 < lane) {
                    float4 bj = candbox[j2];
                    float ix1 = fmaxf(bj.x, bi.x);
                    float iy1 = fmaxf(bj.y, bi.y);
                    float ix2 = fminf(bj.z, bi.z);
                    float iy2 = fminf(bj.w, bi.w);
                    float iw  = fmaxf(__fsub_rn(ix2, ix1), 0.0f);
                    float ih  = fmaxf(__fsub_rn(iy2, iy1), 0.0f);
                    conflict |= (__fmul_rn(iw, ih) > 0.0f);
                }
            }
            bool stop = (ki <= G) || (lane >= BATCH_MAX) || conflict;
            u64 bal = __ballot(stop);                  // lanes>=16 always stop
            int k = __builtin_ctzll(bal);              // k in [0,16]
            if (lane < k) {
                batchkey[lane] = ki;
                batchbox[lane] = bi;
                if (use_lds) okey_lds[mcnt + lane] = ki;
                else { okey[mcnt + lane] = ki; obox[mcnt + lane] = bi; }
            }
            if (lane == 0) nbatchS = k;
        }
        __syncthreads();                               // B_b

        int k = nbatchS;
        if (k == 0) break;                             // all suppressed/selected
        mcnt += k;

        // ---- fused branchless decay: b outer (dynamic), slots inner ----
        // Bit-exact vs serial: per slot the multiply chain runs in batch
        // order (skips where inter==0 are bitwise no-ops via select), kill
        // rule applied per step, matched winners zeroed (earlier in-batch
        // decays on winners are no-ops by pairwise disjointness).
        float scv[CAP];
        bool  alv[CAP], mtc[CAP];
        #pragma unroll
        for (int j = 0; j < CAP; ++j) {
            if (T * j < cnt) {
                scv[j] = __uint_as_float((u32)(key[j] >> 32));
                alv[j] = (key[j] != 0);
                mtc[j] = false;
            }
        }
        for (int b = 0; b < k; ++b) {
            u64    kb = batchkey[b];
            float4 wb = batchbox[b];
            float wx1 = wb.x, wy1 = wb.y, wx2 = wb.z, wy2 = wb.w;
            float warea = __fmul_rn(__fsub_rn(wx2, wx1), __fsub_rn(wy2, wy1));
            #pragma unroll
            for (int j = 0; j < CAP; ++j) {
                if (T * j < cnt) {   // wave-uniform scalar branch
                    float ix1   = fmaxf(wx1, x1r[j]);
                    float iy1   = fmaxf(wy1, y1r[j]);
                    float ix2   = fminf(wx2, x2r[j]);
                    float iy2   = fminf(wy2, y2r[j]);
                    float iw    = fmaxf(__fsub_rn(ix2, ix1), 0.0f);
                    float ih    = fmaxf(__fsub_rn(iy2, iy1), 0.0f);
                    float inter = __fmul_rn(iw, ih);
                    float denom = __fadd_rn(__fsub_rn(__fadd_rn(warea, ar[j]), inter), 1e-8f);
                    float iou   = inter / denom;                // IEEE div
                    float t2    = __fmul_rn(iou, iou);
                    float decay = expf(__fmul_rn(-2.0f, t2));   // exp(-iou^2/0.5)
                    float ns    = __fmul_rn(scv[j], decay);
                    bool  app   = alv[j] && (inter > 0.0f);
                    scv[j] = app ? ns : scv[j];
                    alv[j] = app ? (ns >= SCORE_THR) : alv[j];
                    mtc[j] = mtc[j] || (key[j] == kb);
                }
            }
        }
        #pragma unroll
        for (int j = 0; j < CAP; ++j) {
            if (T * j < cnt) {
                u64 nk = ((u64)__float_as_uint(scv[j]) << 32)
                       | (key[j] & 0xFFFFFFFFull);
                key[j] = (mtc[j] || !alv[j]) ? 0ull : nk;
            }
        }
    }

    // ---- batched flush of staged winners (boxes recovered by rank) ----
    if (use_lds) {
        __syncthreads();
        for (int m = tid; m < mcnt; m += T) {
            u64 w = okey_lds[m];
            okey[m] = w;
            obox[m] = box_lds[(int)(w & 0xFFFF)];
        }
    }
    if (tid == 0) WS_CNT(ws)[cls] = mcnt;
}

// merge the two strictly-descending key lists by rank; pad the tail
__global__ void softnms_merge(void* __restrict__ ws, float* __restrict__ out) {
    int k = blockIdx.x * blockDim.x + threadIdx.x;   // 0..4095
    const u64*    keyA = WS_KEY(ws, 0);
    const u64*    keyB = WS_KEY(ws, 1);
    const float4* boxA = WS_BOX(ws, 0);
    const float4* boxB = WS_BOX(ws, 1);
    const int mA = WS_CNT(ws)[0];
    const int mB = WS_CNT(ws)[1];

    float* ob = out;
    float* os = out + N_BOXES * 4;
    float* ol = out + N_BOXES * 5;

    if (k < mA) {
        u64 x = keyA[k];
        int lo = 0, hi = mB;
        while (lo < hi) { int mid = (lo + hi) >> 1; if (keyB[mid] > x) lo = mid + 1; else hi = mid; }
        int pos = k + lo;
        float4 b = boxA[k];
        ob[pos * 4 + 0] = b.x; ob[pos * 4 + 1] = b.y;
        ob[pos * 4 + 2] = b.z; ob[pos * 4 + 3] = b.w;
        os[pos] = __uint_as_float((u32)(x >> 32));
        ol[pos] = 0.0f;
    } else if (k < mA + mB) {
        int i = k - mA;
        u64 x = keyB[i];
        int lo = 0, hi = mA;
        while (lo < hi) { int mid = (lo + hi) >> 1; if (keyA[mid] > x) lo = mid + 1; else hi = mid; }
        int pos = i + lo;
        float4 b = boxB[i];
        ob[pos * 4 + 0] = b.x; ob[pos * 4 + 1] = b.y;
        ob[pos * 4 + 2] = b.z; ob[pos * 4 + 3] = b.w;
        os[pos] = __uint_as_float((u32)(x >> 32));
        ol[pos] = 1.0f;
    } else {
        ob[k * 4 + 0] = 0.0f; ob[k * 4 + 1] = 0.0f;
        ob[k * 4 + 2] = 0.0f; ob[k * 4 + 3] = 0.0f;
        os[k] = 0.0f;
        ol[k] = -1.0f;
    }
}

extern "C" void kernel_launch(void* const* d_in, const int* in_sizes, int n_in,
                              void* d_out, int out_size, void* d_ws, size_t ws_size,
                              hipStream_t stream) {
    const float* boxes  = (const float*)d_in[0];
    const float* scores = (const float*)d_in[1];
    const int*   labels = (const int*)d_in[2];
    float* out = (float*)d_out;
    (void)in_sizes; (void)n_in; (void)out_size; (void)ws_size;
    softnms_fused<<<2, T, 0, stream>>>(boxes, scores, labels, d_ws);
    softnms_merge<<<N_BOXES / 256, 256, 0, stream>>>(d_ws, out);
}

// Round 3
// 3945.957 us; speedup vs baseline: 1.2966x; 1.1072x over previous
//
#include <hip/hip_runtime.h>
#include <stdint.h>

// SoftNMS (gaussian, sigma=0.5, thr=0.001), N=4096, 2 classes.
// R9: GUARDED IN-REGISTER SIMULATION. R7/R8 batching was guard-starved:
// m2-guard + 32-column cand layout made G ~ 7th-largest key (k~2-5), and the
// 42-shuffle bitonic sort is a ~1us serial ds_bpermute chain per iteration.
// New scheme: post only m1 per thread (cand[tid], 256 entries -> nothing
// column-hidden). G = block-max of per-thread m2 (largest hidden key; hidden
// keys only shrink under decay). EVERY wave redundantly loads all 256
// candidates (4/lane: key+box+area in regs) and runs the serial algorithm
// exactly on them: DPP wave-argmax (no sort), winner box broadcast via
// ballot+readlane (no LDS round trip), then each lane decays its 4 candidate
// copies AND its 8 owned slots with the byte-identical verified FP body.
// Candidate copies decay bit-identically to owner slots => sim-max == true
// global argmax while sim-max > G. No disjointness rule; batch k ~ 20.
// Winners recorded by tid0 during the sim. One barrier pair per batch.

#define N_BOXES 4096
#define T 256
#define CAP 16            // slots/thread capacity (worst case: one class owns all)
#define BOXCAP 2560       // LDS cache capacity (40KB box + 20KB key)
#define SCORE_THR 0.001f

typedef unsigned long long u64;
typedef uint32_t u32;

__device__ __forceinline__ u64 kmax(u64 a, u64 b) { return a > b ? a : b; }
__device__ __forceinline__ u64 kmin(u64 a, u64 b) { return a < b ? a : b; }

// LLVM gfx9 wave64 reduction sequence; identity 0, inputs non-negative.
__device__ __forceinline__ int wave_max_nonneg(int v) {
    v = max(v, __builtin_amdgcn_update_dpp(0, v, 0x111, 0xf, 0xf, false)); // row_shr:1
    v = max(v, __builtin_amdgcn_update_dpp(0, v, 0x112, 0xf, 0xf, false)); // row_shr:2
    v = max(v, __builtin_amdgcn_update_dpp(0, v, 0x114, 0xf, 0xf, false)); // row_shr:4
    v = max(v, __builtin_amdgcn_update_dpp(0, v, 0x118, 0xf, 0xf, false)); // row_shr:8
    v = max(v, __builtin_amdgcn_update_dpp(0, v, 0x142, 0xa, 0xf, false)); // row_bcast:15
    v = max(v, __builtin_amdgcn_update_dpp(0, v, 0x143, 0xc, 0xf, false)); // row_bcast:31
    return __builtin_amdgcn_readlane(v, 63);
}

// exact u64 wave max, two-phase (score bits then tie-break bits); both halves
// are non-negative as ints by construction of the key.
__device__ __forceinline__ u64 wave_max_u64(u64 x) {
    int hi   = (int)(u32)(x >> 32);
    int hmax = wave_max_nonneg(hi);
    int lom  = (hi == hmax) ? (int)(u32)x : 0;
    int lmax = wave_max_nonneg(lom);
    return ((u64)(u32)hmax << 32) | (u64)(u32)lmax;
}

// workspace layout (196624 bytes)
#define WS_KEY(ws, c)  ((u64*)((char*)(ws) + (size_t)(c) * 32768))
#define WS_BOX(ws, c)  ((float4*)((char*)(ws) + 65536 + (size_t)(c) * 65536))
#define WS_CNT(ws)     ((int*)((char*)(ws) + 196608))

__launch_bounds__(T, 1)
__global__ void softnms_fused(const float* __restrict__ boxes,
                              const float* __restrict__ scores,
                              const int* __restrict__ labels,
                              void* __restrict__ ws) {
    const int cls  = blockIdx.x;
    const int tid  = threadIdx.x;
    const int lane = tid & 63;
    const int wid  = tid >> 6;

    __shared__ u64    maskw[64];          // class-membership bitmask
    __shared__ u32    wordpref[64];       // inclusive prefix of popcounts
    __shared__ u64    redG[4];            // per-wave max of per-thread 2nd key
    __shared__ u64    cand[T];            // per-thread m1 posting (256)
    __shared__ float4 box_lds[BOXCAP];
    __shared__ u64    okey_lds[BOXCAP];

    // ---- phase 0a: membership bitmask + popcount prefix ----
    for (int base = 0; base < N_BOXES; base += T) {
        u64 bal = __ballot(labels[base + tid] == cls);
        if (lane == 0) maskw[(base >> 6) + wid] = bal;
    }
    __syncthreads();
    if (wid == 0) {
        u32 v = (u32)__popcll(maskw[lane]);
        #pragma unroll
        for (int d = 1; d < 64; d <<= 1) {
            u32 o = __shfl_up(v, d, 64);
            if (lane >= d) v += o;
        }
        wordpref[lane] = v;
    }
    __syncthreads();
    const int cnt = __builtin_amdgcn_readfirstlane((int)wordpref[63]);

    // ---- phase 0b: rank-select my slots (r = tid + 256*j) -> regs + LDS ----
    float x1r[CAP], y1r[CAP], x2r[CAP], y2r[CAP], ar[CAP];
    u64 key[CAP];
    const float4* boxes4 = reinterpret_cast<const float4*>(boxes);
    #pragma unroll
    for (int j = 0; j < CAP; ++j) {
        key[j] = 0;
        x1r[j] = 0.0f; y1r[j] = 0.0f; x2r[j] = 0.0f; y2r[j] = 0.0f; ar[j] = 0.0f;
        int r = tid + T * j;
        if (r < cnt) {
            int lo = 0, hi = 63;   // smallest word W with wordpref[W] > r
            while (lo < hi) { int mid = (lo + hi) >> 1; if (wordpref[mid] > (u32)r) hi = mid; else lo = mid + 1; }
            int W = lo;
            u32 rb = (W == 0) ? 0u : wordpref[W - 1];
            u32 t = (u32)r - rb;
            u64 x = maskw[W];
            int pos = 0;
            u32 c;
            c = (u32)__popcll(x & 0xFFFFFFFFull); if (t >= c) { pos += 32; t -= c; x >>= 32; }
            c = (u32)__popcll(x & 0xFFFFull);     if (t >= c) { pos += 16; t -= c; x >>= 16; }
            c = (u32)__popcll(x & 0xFFull);       if (t >= c) { pos += 8;  t -= c; x >>= 8; }
            c = (u32)__popcll(x & 0xFull);        if (t >= c) { pos += 4;  t -= c; x >>= 4; }
            c = (u32)__popcll(x & 0x3ull);        if (t >= c) { pos += 2;  t -= c; x >>= 2; }
            c = (u32)__popcll(x & 0x1ull);        if (t >= c) { pos += 1; }
            int g = W * 64 + pos;
            float4 b = boxes4[g];
            x1r[j] = b.x; y1r[j] = b.y; x2r[j] = b.z; y2r[j] = b.w;
            ar[j]  = __fmul_rn(__fsub_rn(b.z, b.x), __fsub_rn(b.w, b.y));
            float s = scores[g];
            // key: score<<32 | (4095-g)<<16 | r   (g: argmax tie-break; r: slot)
            key[j] = ((u64)__float_as_uint(s) << 32)
                   | ((u64)(u32)(4095 - g) << 16) | (u64)(u32)r;
            if (r < BOXCAP) box_lds[r] = b;
        }
    }
    __syncthreads();

    // ---- phase 1: guarded batch simulation ----
    u64*    okey = WS_KEY(ws, cls);
    float4* obox = WS_BOX(ws, cls);
    const bool use_lds = (cnt <= BOXCAP);
    int mcnt = 0;

    for (;;) {
        // gather: per-thread top-2 of live keys (branchless, wave-uniform bound)
        u64 m1 = 0, m2 = 0;
        #pragma unroll
        for (int j = 0; j < CAP; ++j) {
            if (T * j < cnt) {
                u64 kj  = key[j];
                u64 nm1 = kmax(m1, kj);
                m2 = kmax(m2, kmin(m1, kj));
                m1 = nm1;
            }
        }
        u64 wg = wave_max_u64(m2);
        if (lane == 0) redG[wid] = wg;
        cand[tid] = m1;
        __syncthreads();                               // B1: posts visible

        // guard: largest key hidden from the candidate set (only shrinks)
        u64 G = kmax(kmax(redG[0], redG[1]), kmax(redG[2], redG[3]));

        // every wave loads ALL 256 candidates: 4 per lane (key, box, area)
        u64  ck[4];
        float cx1[4], cy1[4], cx2[4], cy2[4], car[4];
        #pragma unroll
        for (int q = 0; q < 4; ++q) {
            u64 c = cand[lane + 64 * q];
            ck[q] = c;
            float4 b;
            if (use_lds) b = box_lds[(int)(c & 0xFFFF)];
            else         b = boxes4[4095 - (int)((c >> 16) & 0xFFFF)];
            cx1[q] = b.x; cy1[q] = b.y; cx2[q] = b.z; cy2[q] = b.w;
            car[q] = __fmul_rn(__fsub_rn(b.z, b.x), __fsub_rn(b.w, b.y));
        }
        __syncthreads();                               // B2: reads done before next posts

        int did = 0;
        for (;;) {
            // exact global argmax while it exceeds the guard
            u64 lm = kmax(kmax(ck[0], ck[1]), kmax(ck[2], ck[3]));
            u64 w  = wave_max_u64(lm);
            if (w <= G) break;

            // winner box broadcast: unique owner lane -> ballot + readlane
            bool q0 = (ck[0] == w), q1 = (ck[1] == w);
            bool q2 = (ck[2] == w), q3 = (ck[3] == w);
            float sx1 = q0 ? cx1[0] : q1 ? cx1[1] : q2 ? cx1[2] : cx1[3];
            float sy1 = q0 ? cy1[0] : q1 ? cy1[1] : q2 ? cy1[2] : cy1[3];
            float sx2 = q0 ? cx2[0] : q1 ? cx2[1] : q2 ? cx2[2] : cx2[3];
            float sy2 = q0 ? cy2[0] : q1 ? cy2[1] : q2 ? cy2[2] : cy2[3];
            u64 ball = __ballot(q0 | q1 | q2 | q3);
            int src  = (int)__builtin_ctzll(ball);
            float wx1 = __uint_as_float(__builtin_amdgcn_readlane(__float_as_uint(sx1), src));
            float wy1 = __uint_as_float(__builtin_amdgcn_readlane(__float_as_uint(sy1), src));
            float wx2 = __uint_as_float(__builtin_amdgcn_readlane(__float_as_uint(sx2), src));
            float wy2 = __uint_as_float(__builtin_amdgcn_readlane(__float_as_uint(sy2), src));
            float warea = __fmul_rn(__fsub_rn(wx2, wx1), __fsub_rn(wy2, wy1));

            if (tid == 0) {
                if (use_lds) okey_lds[mcnt] = w;
                else { okey[mcnt] = w; obox[mcnt] = make_float4(wx1, wy1, wx2, wy2); }
            }
            mcnt++; did++;

            // decay candidate copies (bit-identical to owner-slot decay)
            #pragma unroll
            for (int q = 0; q < 4; ++q) {
                float ix1   = fmaxf(wx1, cx1[q]);
                float iy1   = fmaxf(wy1, cy1[q]);
                float ix2   = fminf(wx2, cx2[q]);
                float iy2   = fminf(wy2, cy2[q]);
                float iw    = fmaxf(__fsub_rn(ix2, ix1), 0.0f);
                float ih    = fmaxf(__fsub_rn(iy2, iy1), 0.0f);
                float inter = __fmul_rn(iw, ih);
                float denom = __fadd_rn(__fsub_rn(__fadd_rn(warea, car[q]), inter), 1e-8f);
                float iou   = inter / denom;                // IEEE div
                float t2    = __fmul_rn(iou, iou);
                float decay = expf(__fmul_rn(-2.0f, t2));   // exp(-iou^2/0.5)
                float sc    = __uint_as_float((u32)(ck[q] >> 32));
                float ns    = __fmul_rn(sc, decay);
                bool  app   = (ck[q] != 0) && (inter > 0.0f);
                u64   nk    = ((u64)__float_as_uint(ns) << 32) | (ck[q] & 0xFFFFFFFFull);
                u64   upd   = app ? ((ns >= SCORE_THR) ? nk : 0ull) : ck[q];
                ck[q] = (ck[q] == w) ? 0ull : upd;
            }
            // decay owned slots (main state) with the same exact body
            #pragma unroll
            for (int j = 0; j < CAP; ++j) {
                if (T * j < cnt) {
                    u64 kj = key[j];
                    float ix1   = fmaxf(wx1, x1r[j]);
                    float iy1   = fmaxf(wy1, y1r[j]);
                    float ix2   = fminf(wx2, x2r[j]);
                    float iy2   = fminf(wy2, y2r[j]);
                    float iw    = fmaxf(__fsub_rn(ix2, ix1), 0.0f);
                    float ih    = fmaxf(__fsub_rn(iy2, iy1), 0.0f);
                    float inter = __fmul_rn(iw, ih);
                    float denom = __fadd_rn(__fsub_rn(__fadd_rn(warea, ar[j]), inter), 1e-8f);
                    float iou   = inter / denom;                // IEEE div
                    float t2    = __fmul_rn(iou, iou);
                    float decay = expf(__fmul_rn(-2.0f, t2));   // exp(-iou^2/0.5)
                    float sc    = __uint_as_float((u32)(kj >> 32));
                    float ns    = __fmul_rn(sc, decay);
                    bool  app   = (kj != 0) && (inter > 0.0f);
                    u64   nk    = ((u64)__float_as_uint(ns) << 32) | (kj & 0xFFFFFFFFull);
                    u64   upd   = app ? ((ns >= SCORE_THR) ? nk : 0ull) : kj;
                    key[j] = (kj == w) ? 0ull : upd;
                }
            }
        }
        if (did == 0) break;   // sim-max <= G possible only when all keys dead
    }

    // ---- batched flush of staged winners (boxes recovered by rank) ----
    if (use_lds) {
        __syncthreads();
        for (int m = tid; m < mcnt; m += T) {
            u64 w = okey_lds[m];
            okey[m] = w;
            obox[m] = box_lds[(int)(w & 0xFFFF)];
        }
    }
    if (tid == 0) WS_CNT(ws)[cls] = mcnt;
}

// merge the two strictly-descending key lists by rank; pad the tail
__global__ void softnms_merge(void* __restrict__ ws, float* __restrict__ out) {
    int k = blockIdx.x * blockDim.x + threadIdx.x;   // 0..4095
    const u64*    keyA = WS_KEY(ws, 0);
    const u64*    keyB = WS_KEY(ws, 1);
    const float4* boxA = WS_BOX(ws, 0);
    const float4* boxB = WS_BOX(ws, 1);
    const int mA = WS_CNT(ws)[0];
    const int mB = WS_CNT(ws)[1];

    float* ob = out;
    float* os = out + N_BOXES * 4;
    float* ol = out + N_BOXES * 5;

    if (k < mA) {
        u64 x = keyA[k];
        int lo = 0, hi = mB;
        while (lo < hi) { int mid = (lo + hi) >> 1; if (keyB[mid] > x) lo = mid + 1; else hi = mid; }
        int pos = k + lo;
        float4 b = boxA[k];
        ob[pos * 4 + 0] = b.x; ob[pos * 4 + 1] = b.y;
        ob[pos * 4 + 2] = b.z; ob[pos * 4 + 3] = b.w;
        os[pos] = __uint_as_float((u32)(x >> 32));
        ol[pos] = 0.0f;
    } else if (k < mA + mB) {
        int i = k - mA;
        u64 x = keyB[i];
        int lo = 0, hi = mA;
        while (lo < hi) { int mid = (lo + hi) >> 1; if (keyA[mid] > x) lo = mid + 1; else hi = mid; }
        int pos = i + lo;
        float4 b = boxB[i];
        ob[pos * 4 + 0] = b.x; ob[pos * 4 + 1] = b.y;
        ob[pos * 4 + 2] = b.z; ob[pos * 4 + 3] = b.w;
        os[pos] = __uint_as_float((u32)(x >> 32));
        ol[pos] = 1.0f;
    } else {
        ob[k * 4 + 0] = 0.0f; ob[k * 4 + 1] = 0.0f;
        ob[k * 4 + 2] = 0.0f; ob[k * 4 + 3] = 0.0f;
        os[k] = 0.0f;
        ol[k] = -1.0f;
    }
}

extern "C" void kernel_launch(void* const* d_in, const int* in_sizes, int n_in,
                              void* d_out, int out_size, void* d_ws, size_t ws_size,
                              hipStream_t stream) {
    const float* boxes  = (const float*)d_in[0];
    const float* scores = (const float*)d_in[1];
    const int*   labels = (const int*)d_in[2];
    float* out = (float*)d_out;
    (void)in_sizes; (void)n_in; (void)out_size; (void)ws_size;
    softnms_fused<<<2, T, 0, stream>>>(boxes, scores, labels, d_ws);
    softnms_merge<<<N_BOXES / 256, 256, 0, stream>>>(d_ws, out);
}

// Round 5
// 2969.192 us; speedup vs baseline: 1.7231x; 1.3290x over previous
//
#include <hip/hip_runtime.h>
#include <stdint.h>

// SoftNMS (gaussian, sigma=0.5, thr=0.001), N=4096, 2 classes.
// R11: RESUBMIT of R10 (container-level infra failure, no measurement).
// Re-audited for hangs: all barriers uniform (waves compute identical
// argmax from identical redundant candidate copies), no LDS races
// (reads/writes separated by B1/B2), guaranteed progress (unique keys =>
// max(m1) > max(m2) = G whenever any key lives; winner always self-hits
// so replay zeroes it). No code change vs R10.
//
// R10: THIN BODIES + DEFERRED SLOT REPLAY. R9 measured ~1500 VALU instr per
// selection: 12 full decay bodies (4 cand copies + 8 owned slots), each ~60
// instr (IEEE div ~15, ocml expf ~18, u64 pack/selects ~12). This round keeps
// R9's guarded-simulation structure (bit-exact) and cuts the per-selection
// body count/fatness:
//  (1) owned slots: per selection only a geometry hit-test -> bitmask
//      (13 instr/slot); full exact body replayed at batch end on set bits
//      only, in ascending batch order (bit-exact: skip at inter==0 is the
//      serial no-op; order + kill rule preserved).
//  (2) candidates: float score + u32 static instead of u64 keys; two-phase
//      DPP argmax (float order == uint order for non-neg scores); static-only
//      winner matching (statics unique); dead = score 0.0f; explicit all-dead
//      stop at hmax==0.
//  (3) batch capped at 64 (mask width); cap-split is guard-exact.

#define N_BOXES 4096
#define T 256
#define CAP 16            // slots/thread capacity (worst case: one class owns all)
#define BOXCAP 2560       // LDS cache capacity (40KB box + 20KB key)
#define SCORE_THR 0.001f
#define BMAX 64           // batch cap (hit-bitmask width)

typedef unsigned long long u64;
typedef uint32_t u32;

__device__ __forceinline__ u64 kmax(u64 a, u64 b) { return a > b ? a : b; }
__device__ __forceinline__ u64 kmin(u64 a, u64 b) { return a < b ? a : b; }

// LLVM gfx9 wave64 reduction sequence; identity 0, inputs non-negative.
__device__ __forceinline__ int wave_max_nonneg(int v) {
    v = max(v, __builtin_amdgcn_update_dpp(0, v, 0x111, 0xf, 0xf, false)); // row_shr:1
    v = max(v, __builtin_amdgcn_update_dpp(0, v, 0x112, 0xf, 0xf, false)); // row_shr:2
    v = max(v, __builtin_amdgcn_update_dpp(0, v, 0x114, 0xf, 0xf, false)); // row_shr:4
    v = max(v, __builtin_amdgcn_update_dpp(0, v, 0x118, 0xf, 0xf, false)); // row_shr:8
    v = max(v, __builtin_amdgcn_update_dpp(0, v, 0x142, 0xa, 0xf, false)); // row_bcast:15
    v = max(v, __builtin_amdgcn_update_dpp(0, v, 0x143, 0xc, 0xf, false)); // row_bcast:31
    return __builtin_amdgcn_readlane(v, 63);
}

// exact u64 wave max, two-phase (score bits then tie-break bits).
__device__ __forceinline__ u64 wave_max_u64(u64 x) {
    int hi   = (int)(u32)(x >> 32);
    int hmax = wave_max_nonneg(hi);
    int lom  = (hi == hmax) ? (int)(u32)x : 0;
    int lmax = wave_max_nonneg(lom);
    return ((u64)(u32)hmax << 32) | (u64)(u32)lmax;
}

// workspace layout (196624 bytes)
#define WS_KEY(ws, c)  ((u64*)((char*)(ws) + (size_t)(c) * 32768))
#define WS_BOX(ws, c)  ((float4*)((char*)(ws) + 65536 + (size_t)(c) * 65536))
#define WS_CNT(ws)     ((int*)((char*)(ws) + 196608))

__launch_bounds__(T, 1)
__global__ void softnms_fused(const float* __restrict__ boxes,
                              const float* __restrict__ scores,
                              const int* __restrict__ labels,
                              void* __restrict__ ws) {
    const int cls  = blockIdx.x;
    const int tid  = threadIdx.x;
    const int lane = tid & 63;
    const int wid  = tid >> 6;

    __shared__ u64    maskw[64];          // class-membership bitmask
    __shared__ u32    wordpref[64];       // inclusive prefix of popcounts
    __shared__ u64    redG[4];            // per-wave max of per-thread 2nd key
    __shared__ u64    cand[T];            // per-thread m1 posting (256)
    __shared__ float4 batchbox[BMAX];     // winner boxes of current batch
    __shared__ u32    batchstat[BMAX];    // winner statics of current batch
    __shared__ float4 box_lds[BOXCAP];
    __shared__ u64    okey_lds[BOXCAP];

    // ---- phase 0a: membership bitmask + popcount prefix ----
    for (int base = 0; base < N_BOXES; base += T) {
        u64 bal = __ballot(labels[base + tid] == cls);
        if (lane == 0) maskw[(base >> 6) + wid] = bal;
    }
    __syncthreads();
    if (wid == 0) {
        u32 v = (u32)__popcll(maskw[lane]);
        #pragma unroll
        for (int d = 1; d < 64; d <<= 1) {
            u32 o = __shfl_up(v, d, 64);
            if (lane >= d) v += o;
        }
        wordpref[lane] = v;
    }
    __syncthreads();
    const int cnt = __builtin_amdgcn_readfirstlane((int)wordpref[63]);

    // ---- phase 0b: rank-select my slots (r = tid + 256*j) -> regs + LDS ----
    float x1r[CAP], y1r[CAP], x2r[CAP], y2r[CAP], ar[CAP];
    u64 key[CAP];
    const float4* boxes4 = reinterpret_cast<const float4*>(boxes);
    #pragma unroll
    for (int j = 0; j < CAP; ++j) {
        key[j] = 0;
        x1r[j] = 0.0f; y1r[j] = 0.0f; x2r[j] = 0.0f; y2r[j] = 0.0f; ar[j] = 0.0f;
        int r = tid + T * j;
        if (r < cnt) {
            int lo = 0, hi = 63;   // smallest word W with wordpref[W] > r
            while (lo < hi) { int mid = (lo + hi) >> 1; if (wordpref[mid] > (u32)r) hi = mid; else lo = mid + 1; }
            int W = lo;
            u32 rb = (W == 0) ? 0u : wordpref[W - 1];
            u32 t = (u32)r - rb;
            u64 x = maskw[W];
            int pos = 0;
            u32 c;
            c = (u32)__popcll(x & 0xFFFFFFFFull); if (t >= c) { pos += 32; t -= c; x >>= 32; }
            c = (u32)__popcll(x & 0xFFFFull);     if (t >= c) { pos += 16; t -= c; x >>= 16; }
            c = (u32)__popcll(x & 0xFFull);       if (t >= c) { pos += 8;  t -= c; x >>= 8; }
            c = (u32)__popcll(x & 0xFull);        if (t >= c) { pos += 4;  t -= c; x >>= 4; }
            c = (u32)__popcll(x & 0x3ull);        if (t >= c) { pos += 2;  t -= c; x >>= 2; }
            c = (u32)__popcll(x & 0x1ull);        if (t >= c) { pos += 1; }
            int g = W * 64 + pos;
            float4 b = boxes4[g];
            x1r[j] = b.x; y1r[j] = b.y; x2r[j] = b.z; y2r[j] = b.w;
            ar[j]  = __fmul_rn(__fsub_rn(b.z, b.x), __fsub_rn(b.w, b.y));
            float s = scores[g];
            // key: score<<32 | (4095-g)<<16 | r   (g: argmax tie-break; r: slot)
            key[j] = ((u64)__float_as_uint(s) << 32)
                   | ((u64)(u32)(4095 - g) << 16) | (u64)(u32)r;
            if (r < BOXCAP) box_lds[r] = b;
        }
    }
    __syncthreads();

    // ---- phase 1: guarded batch simulation ----
    u64*    okey = WS_KEY(ws, cls);
    float4* obox = WS_BOX(ws, cls);
    const bool use_lds = (cnt <= BOXCAP);
    int mcnt = 0;

    for (;;) {
        // gather: per-thread top-2 of live keys (u64, branchless)
        u64 m1 = 0, m2 = 0;
        #pragma unroll
        for (int j = 0; j < CAP; ++j) {
            if (T * j < cnt) {
                u64 kj  = key[j];
                u64 nm1 = kmax(m1, kj);
                m2 = kmax(m2, kmin(m1, kj));
                m1 = nm1;
            }
        }
        u64 wg = wave_max_u64(m2);
        if (lane == 0) redG[wid] = wg;
        cand[tid] = m1;
        __syncthreads();                               // B1

        u64 G = kmax(kmax(redG[0], redG[1]), kmax(redG[2], redG[3]));
        const u32 Ghi = (u32)(G >> 32), Glo = (u32)G;

        // every wave loads ALL 256 candidates: (score, static, box, area)
        float csc[4]; u32 cst[4];
        float cx1[4], cy1[4], cx2[4], cy2[4], car[4];
        #pragma unroll
        for (int q = 0; q < 4; ++q) {
            u64 c = cand[lane + 64 * q];
            csc[q] = __uint_as_float((u32)(c >> 32));
            cst[q] = (u32)c;
            float4 b;
            if (use_lds) b = box_lds[(int)(c & 0xFFFF)];
            else         b = boxes4[4095 - (int)((c >> 16) & 0xFFFF)];
            cx1[q] = b.x; cy1[q] = b.y; cx2[q] = b.z; cy2[q] = b.w;
            car[q] = __fmul_rn(__fsub_rn(b.z, b.x), __fsub_rn(b.w, b.y));
        }

        u64 hm[CAP];                                   // per-slot hit bitmasks
        #pragma unroll
        for (int j = 0; j < CAP; ++j) hm[j] = 0;

        int did = 0;
        for (;;) {
            // two-phase argmax: float score (== uint order, non-neg), then static
            float ls = fmaxf(fmaxf(csc[0], csc[1]), fmaxf(csc[2], csc[3]));
            u32 lsb = __float_as_uint(ls);
            u32 lst = 0;
            #pragma unroll
            for (int q = 0; q < 4; ++q)
                lst = (__float_as_uint(csc[q]) == lsb) ? (lst > cst[q] ? lst : cst[q]) : lst;
            int hmax = wave_max_nonneg((int)lsb);
            int lom  = ((int)lsb == hmax) ? (int)lst : 0;
            int lmax = wave_max_nonneg(lom);
            const u32 uh = (u32)hmax, ul = (u32)lmax;
            if (uh == 0u) break;                                  // all dead
            if (uh < Ghi || (uh == Ghi && ul <= Glo)) break;      // guard stop
            if (did == BMAX) break;                               // mask width

            // winner box broadcast (static match is unique)
            bool w0 = (cst[0] == ul), w1 = (cst[1] == ul);
            bool w2 = (cst[2] == ul), w3 = (cst[3] == ul);
            float sx1 = w0 ? cx1[0] : w1 ? cx1[1] : w2 ? cx1[2] : cx1[3];
            float sy1 = w0 ? cy1[0] : w1 ? cy1[1] : w2 ? cy1[2] : cy1[3];
            float sx2 = w0 ? cx2[0] : w1 ? cx2[1] : w2 ? cx2[2] : cx2[3];
            float sy2 = w0 ? cy2[0] : w1 ? cy2[1] : w2 ? cy2[2] : cy2[3];
            u64 ball = __ballot(w0 | w1 | w2 | w3);
            int src  = (int)__builtin_ctzll(ball);
            float wx1 = __uint_as_float(__builtin_amdgcn_readlane(__float_as_uint(sx1), src));
            float wy1 = __uint_as_float(__builtin_amdgcn_readlane(__float_as_uint(sy1), src));
            float wx2 = __uint_as_float(__builtin_amdgcn_readlane(__float_as_uint(sx2), src));
            float wy2 = __uint_as_float(__builtin_amdgcn_readlane(__float_as_uint(sy2), src));
            float warea = __fmul_rn(__fsub_rn(wx2, wx1), __fsub_rn(wy2, wy1));

            if (tid == 0) {
                u64 w = ((u64)uh << 32) | (u64)ul;
                if (use_lds) okey_lds[mcnt] = w;
                else { okey[mcnt] = w; obox[mcnt] = make_float4(wx1, wy1, wx2, wy2); }
                batchbox[did]  = make_float4(wx1, wy1, wx2, wy2);
                batchstat[did] = ul;
            }

            // decay candidate copies (thin, float-only; bit-exact chain)
            #pragma unroll
            for (int q = 0; q < 4; ++q) {
                float ix1   = fmaxf(wx1, cx1[q]);
                float iy1   = fmaxf(wy1, cy1[q]);
                float ix2   = fminf(wx2, cx2[q]);
                float iy2   = fminf(wy2, cy2[q]);
                float iw    = fmaxf(__fsub_rn(ix2, ix1), 0.0f);
                float ih    = fmaxf(__fsub_rn(iy2, iy1), 0.0f);
                float inter = __fmul_rn(iw, ih);
                float denom = __fadd_rn(__fsub_rn(__fadd_rn(warea, car[q]), inter), 1e-8f);
                float iou   = inter / denom;                // IEEE div
                float t2    = __fmul_rn(iou, iou);
                float decay = expf(__fmul_rn(-2.0f, t2));   // exp(-iou^2/0.5)
                float ns    = __fmul_rn(csc[q], decay);
                float kept  = (ns >= SCORE_THR) ? ns : 0.0f;
                float nsc   = (inter > 0.0f) ? kept : csc[q];
                csc[q] = (cst[q] == ul) ? 0.0f : nsc;
            }

            // owned slots: geometry hit-test only -> bitmask (full body deferred)
            u64 bit = 1ull << did;
            #pragma unroll
            for (int j = 0; j < CAP; ++j) {
                if (T * j < cnt) {
                    float ix1 = fmaxf(wx1, x1r[j]);
                    float iy1 = fmaxf(wy1, y1r[j]);
                    float ix2 = fminf(wx2, x2r[j]);
                    float iy2 = fminf(wy2, y2r[j]);
                    float iw  = fmaxf(__fsub_rn(ix2, ix1), 0.0f);
                    float ih  = fmaxf(__fsub_rn(iy2, iy1), 0.0f);
                    bool hit  = __fmul_rn(iw, ih) > 0.0f;
                    hm[j] = hit ? (hm[j] | bit) : hm[j];
                }
            }
            mcnt++; did++;
        }
        if (did == 0) break;                           // all keys dead
        __syncthreads();                               // B2: batch arrays visible

        // replay: apply full exact body on set bits, ascending batch order
        #pragma unroll
        for (int j = 0; j < CAP; ++j) {
            if (T * j < cnt) {
                u64 m = hm[j];
                while (m) {
                    int b = (int)__builtin_ctzll(m);
                    m &= (m - 1);
                    float4 wb = batchbox[b];
                    u32   wst = batchstat[b];
                    float wx1 = wb.x, wy1 = wb.y, wx2 = wb.z, wy2 = wb.w;
                    float warea = __fmul_rn(__fsub_rn(wx2, wx1), __fsub_rn(wy2, wy1));
                    u64 kj = key[j];
                    float ix1   = fmaxf(wx1, x1r[j]);
                    float iy1   = fmaxf(wy1, y1r[j]);
                    float ix2   = fminf(wx2, x2r[j]);
                    float iy2   = fminf(wy2, y2r[j]);
                    float iw    = fmaxf(__fsub_rn(ix2, ix1), 0.0f);
                    float ih    = fmaxf(__fsub_rn(iy2, iy1), 0.0f);
                    float inter = __fmul_rn(iw, ih);
                    float denom = __fadd_rn(__fsub_rn(__fadd_rn(warea, ar[j]), inter), 1e-8f);
                    float iou   = inter / denom;                // IEEE div
                    float t2    = __fmul_rn(iou, iou);
                    float decay = expf(__fmul_rn(-2.0f, t2));   // exp(-iou^2/0.5)
                    float sc    = __uint_as_float((u32)(kj >> 32));
                    float ns    = __fmul_rn(sc, decay);
                    bool  app   = (kj != 0) && (inter > 0.0f);
                    u64   nk    = ((u64)__float_as_uint(ns) << 32) | (kj & 0xFFFFFFFFull);
                    u64   upd   = app ? ((ns >= SCORE_THR) ? nk : 0ull) : kj;
                    key[j] = ((u32)kj == wst) ? 0ull : upd;     // winner-zero (static unique)
                }
            }
        }
    }

    // ---- batched flush of staged winners (boxes recovered by rank) ----
    if (use_lds) {
        __syncthreads();
        for (int m = tid; m < mcnt; m += T) {
            u64 w = okey_lds[m];
            okey[m] = w;
            obox[m] = box_lds[(int)(w & 0xFFFF)];
        }
    }
    if (tid == 0) WS_CNT(ws)[cls] = mcnt;
}

// merge the two strictly-descending key lists by rank; pad the tail
__global__ void softnms_merge(void* __restrict__ ws, float* __restrict__ out) {
    int k = blockIdx.x * blockDim.x + threadIdx.x;   // 0..4095
    const u64*    keyA = WS_KEY(ws, 0);
    const u64*    keyB = WS_KEY(ws, 1);
    const float4* boxA = WS_BOX(ws, 0);
    const float4* boxB = WS_BOX(ws, 1);
    const int mA = WS_CNT(ws)[0];
    const int mB = WS_CNT(ws)[1];

    float* ob = out;
    float* os = out + N_BOXES * 4;
    float* ol = out + N_BOXES * 5;

    if (k < mA) {
        u64 x = keyA[k];
        int lo = 0, hi = mB;
        while (lo < hi) { int mid = (lo + hi) >> 1; if (keyB[mid] > x) lo = mid + 1; else hi = mid; }
        int pos = k + lo;
        float4 b = boxA[k];
        ob[pos * 4 + 0] = b.x; ob[pos * 4 + 1] = b.y;
        ob[pos * 4 + 2] = b.z; ob[pos * 4 + 3] = b.w;
        os[pos] = __uint_as_float((u32)(x >> 32));
        ol[pos] = 0.0f;
    } else if (k < mA + mB) {
        int i = k - mA;
        u64 x = keyB[i];
        int lo = 0, hi = mA;
        while (lo < hi) { int mid = (lo + hi) >> 1; if (keyA[mid] > x) lo = mid + 1; else hi = mid; }
        int pos = i + lo;
        float4 b = boxB[i];
        ob[pos * 4 + 0] = b.x; ob[pos * 4 + 1] = b.y;
        ob[pos * 4 + 2] = b.z; ob[pos * 4 + 3] = b.w;
        os[pos] = __uint_as_float((u32)(x >> 32));
        ol[pos] = 1.0f;
    } else {
        ob[k * 4 + 0] = 0.0f; ob[k * 4 + 1] = 0.0f;
        ob[k * 4 + 2] = 0.0f; ob[k * 4 + 3] = 0.0f;
        os[k] = 0.0f;
        ol[k] = -1.0f;
    }
}

extern "C" void kernel_launch(void* const* d_in, const int* in_sizes, int n_in,
                              void* d_out, int out_size, void* d_ws, size_t ws_size,
                              hipStream_t stream) {
    const float* boxes  = (const float*)d_in[0];
    const float* scores = (const float*)d_in[1];
    const int*   labels = (const int*)d_in[2];
    float* out = (float*)d_out;
    (void)in_sizes; (void)n_in; (void)out_size; (void)ws_size;
    softnms_fused<<<2, T, 0, stream>>>(boxes, scores, labels, d_ws);
    softnms_merge<<<N_BOXES / 256, 256, 0, stream>>>(d_ws, out);
}

// Round 6
// 2693.944 us; speedup vs baseline: 1.8992x; 1.1022x over previous
//
#include <hip/hip_runtime.h>
#include <stdint.h>

// SoftNMS (gaussian, sigma=0.5, thr=0.001), N=4096, 2 classes.
// R12: SECOND-LEVEL GUARD + SINGLE-CANDIDATE SIM. R11 measured ~1000 instr
// per selection; the three structural cuts here:
//  (1) lane-level guard: per batch each lane keeps only the MAX of its 4
//      candidates; lane 2nd-max folds into the guard
//      G = max(block-max m2, wave-max lane-m2'). Same exactness proof as the
//      thread-level guard (hidden values <= G and only shrink; global max is
//      always a lane max, so strict progress). Candidate decay 4x -> 1x per
//      selection; batch ~20 -> ~11 (overhead amortization still fine).
//  (2) tie-break DPP chain (2nd 6-step reduce) only when a bitwise score tie
//      actually exists (wave-uniform ballot check) - ties are ~never.
//  (3) hit tests in exact 4-compare overlap form (valid boxes); replay
//      re-derives the apply predicate, so bits are a pure filter. u32 masks
//      (BMAX=32; cap-split is guard-exact).
// All decay FP bodies byte-identical to the verified serial chain.

#define N_BOXES 4096
#define T 256
#define CAP 16            // slots/thread capacity (worst case: one class owns all)
#define BOXCAP 2560       // LDS cache capacity (40KB box + 20KB key)
#define SCORE_THR 0.001f
#define BMAX 32           // batch cap (u32 hit-bitmask width)

typedef unsigned long long u64;
typedef uint32_t u32;

__device__ __forceinline__ u64 kmax(u64 a, u64 b) { return a > b ? a : b; }
__device__ __forceinline__ u64 kmin(u64 a, u64 b) { return a < b ? a : b; }

// LLVM gfx9 wave64 reduction sequence; identity 0, inputs non-negative.
__device__ __forceinline__ int wave_max_nonneg(int v) {
    v = max(v, __builtin_amdgcn_update_dpp(0, v, 0x111, 0xf, 0xf, false)); // row_shr:1
    v = max(v, __builtin_amdgcn_update_dpp(0, v, 0x112, 0xf, 0xf, false)); // row_shr:2
    v = max(v, __builtin_amdgcn_update_dpp(0, v, 0x114, 0xf, 0xf, false)); // row_shr:4
    v = max(v, __builtin_amdgcn_update_dpp(0, v, 0x118, 0xf, 0xf, false)); // row_shr:8
    v = max(v, __builtin_amdgcn_update_dpp(0, v, 0x142, 0xa, 0xf, false)); // row_bcast:15
    v = max(v, __builtin_amdgcn_update_dpp(0, v, 0x143, 0xc, 0xf, false)); // row_bcast:31
    return __builtin_amdgcn_readlane(v, 63);
}

// exact u64 wave max, two-phase (score bits then tie-break bits).
__device__ __forceinline__ u64 wave_max_u64(u64 x) {
    int hi   = (int)(u32)(x >> 32);
    int hmax = wave_max_nonneg(hi);
    int lom  = (hi == hmax) ? (int)(u32)x : 0;
    int lmax = wave_max_nonneg(lom);
    return ((u64)(u32)hmax << 32) | (u64)(u32)lmax;
}

__device__ __forceinline__ float readlane_f(float v, int l) {
    return __uint_as_float((u32)__builtin_amdgcn_readlane((int)__float_as_uint(v), l));
}

// workspace layout (196624 bytes)
#define WS_KEY(ws, c)  ((u64*)((char*)(ws) + (size_t)(c) * 32768))
#define WS_BOX(ws, c)  ((float4*)((char*)(ws) + 65536 + (size_t)(c) * 65536))
#define WS_CNT(ws)     ((int*)((char*)(ws) + 196608))

__launch_bounds__(T, 1)
__global__ void softnms_fused(const float* __restrict__ boxes,
                              const float* __restrict__ scores,
                              const int* __restrict__ labels,
                              void* __restrict__ ws) {
    const int cls  = blockIdx.x;
    const int tid  = threadIdx.x;
    const int lane = tid & 63;
    const int wid  = tid >> 6;

    __shared__ u64    maskw[64];          // class-membership bitmask
    __shared__ u32    wordpref[64];       // inclusive prefix of popcounts
    __shared__ u64    redG[4];            // per-wave max of per-thread 2nd key
    __shared__ u64    cand[T];            // per-thread m1 posting (256)
    __shared__ float4 batchbox[BMAX];     // winner boxes of current batch
    __shared__ u32    batchstat[BMAX];    // winner statics of current batch
    __shared__ float4 box_lds[BOXCAP];
    __shared__ u64    okey_lds[BOXCAP];

    // ---- phase 0a: membership bitmask + popcount prefix ----
    for (int base = 0; base < N_BOXES; base += T) {
        u64 bal = __ballot(labels[base + tid] == cls);
        if (lane == 0) maskw[(base >> 6) + wid] = bal;
    }
    __syncthreads();
    if (wid == 0) {
        u32 v = (u32)__popcll(maskw[lane]);
        #pragma unroll
        for (int d = 1; d < 64; d <<= 1) {
            u32 o = __shfl_up(v, d, 64);
            if (lane >= d) v += o;
        }
        wordpref[lane] = v;
    }
    __syncthreads();
    const int cnt = __builtin_amdgcn_readfirstlane((int)wordpref[63]);

    // ---- phase 0b: rank-select my slots (r = tid + 256*j) -> regs + LDS ----
    float x1r[CAP], y1r[CAP], x2r[CAP], y2r[CAP], ar[CAP];
    u64 key[CAP];
    const float4* boxes4 = reinterpret_cast<const float4*>(boxes);
    #pragma unroll
    for (int j = 0; j < CAP; ++j) {
        key[j] = 0;
        x1r[j] = 0.0f; y1r[j] = 0.0f; x2r[j] = 0.0f; y2r[j] = 0.0f; ar[j] = 0.0f;
        int r = tid + T * j;
        if (r < cnt) {
            int lo = 0, hi = 63;   // smallest word W with wordpref[W] > r
            while (lo < hi) { int mid = (lo + hi) >> 1; if (wordpref[mid] > (u32)r) hi = mid; else lo = mid + 1; }
            int W = lo;
            u32 rb = (W == 0) ? 0u : wordpref[W - 1];
            u32 t = (u32)r - rb;
            u64 x = maskw[W];
            int pos = 0;
            u32 c;
            c = (u32)__popcll(x & 0xFFFFFFFFull); if (t >= c) { pos += 32; t -= c; x >>= 32; }
            c = (u32)__popcll(x & 0xFFFFull);     if (t >= c) { pos += 16; t -= c; x >>= 16; }
            c = (u32)__popcll(x & 0xFFull);       if (t >= c) { pos += 8;  t -= c; x >>= 8; }
            c = (u32)__popcll(x & 0xFull);        if (t >= c) { pos += 4;  t -= c; x >>= 4; }
            c = (u32)__popcll(x & 0x3ull);        if (t >= c) { pos += 2;  t -= c; x >>= 2; }
            c = (u32)__popcll(x & 0x1ull);        if (t >= c) { pos += 1; }
            int g = W * 64 + pos;
            float4 b = boxes4[g];
            x1r[j] = b.x; y1r[j] = b.y; x2r[j] = b.z; y2r[j] = b.w;
            ar[j]  = __fmul_rn(__fsub_rn(b.z, b.x), __fsub_rn(b.w, b.y));
            float s = scores[g];
            // key: score<<32 | (4095-g)<<16 | r   (g: argmax tie-break; r: slot)
            key[j] = ((u64)__float_as_uint(s) << 32)
                   | ((u64)(u32)(4095 - g) << 16) | (u64)(u32)r;
            if (r < BOXCAP) box_lds[r] = b;
        }
    }
    __syncthreads();

    // ---- phase 1: guarded batch simulation (single candidate per lane) ----
    u64*    okey = WS_KEY(ws, cls);
    float4* obox = WS_BOX(ws, cls);
    const bool use_lds = (cnt <= BOXCAP);
    int mcnt = 0;

    for (;;) {
        // gather: per-thread top-2 of live keys (u64, branchless)
        u64 m1 = 0, m2 = 0;
        #pragma unroll
        for (int j = 0; j < CAP; ++j) {
            if (T * j < cnt) {
                u64 kj  = key[j];
                u64 nm1 = kmax(m1, kj);
                m2 = kmax(m2, kmin(m1, kj));
                m1 = nm1;
            }
        }
        u64 wg = wave_max_u64(m2);
        if (lane == 0) redG[wid] = wg;
        cand[tid] = m1;
        __syncthreads();                               // B1

        // level-2: lane keeps only its max of 4 candidates; 2nd folds into G
        u64 c1 = 0, c2 = 0;
        #pragma unroll
        for (int q = 0; q < 4; ++q) {
            u64 c  = cand[lane + 64 * q];
            u64 n1 = kmax(c1, c);
            c2 = kmax(c2, kmin(c1, c));
            c1 = n1;
        }
        u64 G = kmax(kmax(kmax(redG[0], redG[1]), kmax(redG[2], redG[3])),
                     wave_max_u64(c2));
        const u32 Ghi = (u32)(G >> 32), Glo = (u32)G;

        u32 cscb = (u32)(c1 >> 32);                    // score bits (non-neg)
        u32 cst  = (u32)c1;                            // static (unique)
        float4 cb;
        if (use_lds) cb = box_lds[(int)(c1 & 0xFFFF)];
        else         cb = boxes4[4095 - (int)((c1 >> 16) & 0xFFFF)];
        float car = __fmul_rn(__fsub_rn(cb.z, cb.x), __fsub_rn(cb.w, cb.y));

        u32 hm[CAP];                                   // per-slot hit bitmasks
        #pragma unroll
        for (int j = 0; j < CAP; ++j) hm[j] = 0;

        int did = 0;
        for (;;) {
            // wave argmax on score bits; tie-break only if a tie exists
            int hmax = wave_max_nonneg((int)cscb);
            const u32 uh = (u32)hmax;
            if (uh == 0u) break;                       // all dead
            if (uh < Ghi) break;                       // guard (fast path)
            u64 tb = __ballot(cscb == uh);
            u32 ul;
            if (__popcll(tb) == 1) {
                ul = (u32)__builtin_amdgcn_readlane((int)cst, (int)__builtin_ctzll(tb));
            } else {
                int lom = (cscb == uh) ? (int)cst : 0;
                ul = (u32)wave_max_nonneg(lom);
            }
            if (uh == Ghi && ul <= Glo) break;         // guard (exact)
            if (did == BMAX) break;                    // mask width

            // winner lane -> broadcast box + area via readlane
            u64 ball2 = __ballot((cscb == uh) & (cst == ul));
            int src = (int)__builtin_ctzll(ball2);
            float wx1 = readlane_f(cb.x, src);
            float wy1 = readlane_f(cb.y, src);
            float wx2 = readlane_f(cb.z, src);
            float wy2 = readlane_f(cb.w, src);
            float warea = readlane_f(car, src);

            if (tid == 0) {
                u64 w = ((u64)uh << 32) | (u64)ul;
                if (use_lds) okey_lds[mcnt] = w;
                else { okey[mcnt] = w; obox[mcnt] = make_float4(wx1, wy1, wx2, wy2); }
                batchbox[did]  = make_float4(wx1, wy1, wx2, wy2);
                batchstat[did] = ul;
            }

            // decay own candidate (thin, float-only; bit-exact chain)
            {
                float csc   = __uint_as_float(cscb);
                float ix1   = fmaxf(wx1, cb.x);
                float iy1   = fmaxf(wy1, cb.y);
                float ix2   = fminf(wx2, cb.z);
                float iy2   = fminf(wy2, cb.w);
                float iw    = fmaxf(__fsub_rn(ix2, ix1), 0.0f);
                float ih    = fmaxf(__fsub_rn(iy2, iy1), 0.0f);
                float inter = __fmul_rn(iw, ih);
                float denom = __fadd_rn(__fsub_rn(__fadd_rn(warea, car), inter), 1e-8f);
                float iou   = inter / denom;                // IEEE div
                float t2    = __fmul_rn(iou, iou);
                float decay = expf(__fmul_rn(-2.0f, t2));   // exp(-iou^2/0.5)
                float ns    = __fmul_rn(csc, decay);
                float kept  = (ns >= SCORE_THR) ? ns : 0.0f;
                float nsc   = (inter > 0.0f) ? kept : csc;
                cscb = (cst == ul) ? 0u : __float_as_uint(nsc);
            }

            // owned slots: 4-compare overlap filter -> bitmask (body deferred)
            u32 bit = 1u << did;
            #pragma unroll
            for (int j = 0; j < CAP; ++j) {
                if (T * j < cnt) {
                    bool hit = (wx2 > x1r[j]) & (x2r[j] > wx1)
                             & (wy2 > y1r[j]) & (y2r[j] > wy1);
                    hm[j] = hit ? (hm[j] | bit) : hm[j];
                }
            }
            mcnt++; did++;
        }
        if (did == 0) break;                           // all keys dead
        __syncthreads();                               // B2: batch arrays visible

        // replay: apply full exact body on set bits, ascending batch order
        #pragma unroll
        for (int j = 0; j < CAP; ++j) {
            if (T * j < cnt) {
                u32 m = hm[j];
                while (m) {
                    int b = (int)__builtin_ctz(m);
                    m &= (m - 1);
                    float4 wb = batchbox[b];
                    u32   wst = batchstat[b];
                    float wx1 = wb.x, wy1 = wb.y, wx2 = wb.z, wy2 = wb.w;
                    float warea = __fmul_rn(__fsub_rn(wx2, wx1), __fsub_rn(wy2, wy1));
                    u64 kj = key[j];
                    float ix1   = fmaxf(wx1, x1r[j]);
                    float iy1   = fmaxf(wy1, y1r[j]);
                    float ix2   = fminf(wx2, x2r[j]);
                    float iy2   = fminf(wy2, y2r[j]);
                    float iw    = fmaxf(__fsub_rn(ix2, ix1), 0.0f);
                    float ih    = fmaxf(__fsub_rn(iy2, iy1), 0.0f);
                    float inter = __fmul_rn(iw, ih);
                    float denom = __fadd_rn(__fsub_rn(__fadd_rn(warea, ar[j]), inter), 1e-8f);
                    float iou   = inter / denom;                // IEEE div
                    float t2    = __fmul_rn(iou, iou);
                    float decay = expf(__fmul_rn(-2.0f, t2));   // exp(-iou^2/0.5)
                    float sc    = __uint_as_float((u32)(kj >> 32));
                    float ns    = __fmul_rn(sc, decay);
                    bool  app   = (kj != 0) && (inter > 0.0f);
                    u64   nk    = ((u64)__float_as_uint(ns) << 32) | (kj & 0xFFFFFFFFull);
                    u64   upd   = app ? ((ns >= SCORE_THR) ? nk : 0ull) : kj;
                    key[j] = ((u32)kj == wst) ? 0ull : upd;     // winner-zero (static unique)
                }
            }
        }
    }

    // ---- batched flush of staged winners (boxes recovered by rank) ----
    if (use_lds) {
        __syncthreads();
        for (int m = tid; m < mcnt; m += T) {
            u64 w = okey_lds[m];
            okey[m] = w;
            obox[m] = box_lds[(int)(w & 0xFFFF)];
        }
    }
    if (tid == 0) WS_CNT(ws)[cls] = mcnt;
}

// merge the two strictly-descending key lists by rank; pad the tail
__global__ void softnms_merge(void* __restrict__ ws, float* __restrict__ out) {
    int k = blockIdx.x * blockDim.x + threadIdx.x;   // 0..4095
    const u64*    keyA = WS_KEY(ws, 0);
    const u64*    keyB = WS_KEY(ws, 1);
    const float4* boxA = WS_BOX(ws, 0);
    const float4* boxB = WS_BOX(ws, 1);
    const int mA = WS_CNT(ws)[0];
    const int mB = WS_CNT(ws)[1];

    float* ob = out;
    float* os = out + N_BOXES * 4;
    float* ol = out + N_BOXES * 5;

    if (k < mA) {
        u64 x = keyA[k];
        int lo = 0, hi = mB;
        while (lo < hi) { int mid = (lo + hi) >> 1; if (keyB[mid] > x) lo = mid + 1; else hi = mid; }
        int pos = k + lo;
        float4 b = boxA[k];
        ob[pos * 4 + 0] = b.x; ob[pos * 4 + 1] = b.y;
        ob[pos * 4 + 2] = b.z; ob[pos * 4 + 3] = b.w;
        os[pos] = __uint_as_float((u32)(x >> 32));
        ol[pos] = 0.0f;
    } else if (k < mA + mB) {
        int i = k - mA;
        u64 x = keyB[i];
        int lo = 0, hi = mA;
        while (lo < hi) { int mid = (lo + hi) >> 1; if (keyA[mid] > x) lo = mid + 1; else hi = mid; }
        int pos = i + lo;
        float4 b = boxB[i];
        ob[pos * 4 + 0] = b.x; ob[pos * 4 + 1] = b.y;
        ob[pos * 4 + 2] = b.z; ob[pos * 4 + 3] = b.w;
        os[pos] = __uint_as_float((u32)(x >> 32));
        ol[pos] = 1.0f;
    } else {
        ob[k * 4 + 0] = 0.0f; ob[k * 4 + 1] = 0.0f;
        ob[k * 4 + 2] = 0.0f; ob[k * 4 + 3] = 0.0f;
        os[k] = 0.0f;
        ol[k] = -1.0f;
    }
}

extern "C" void kernel_launch(void* const* d_in, const int* in_sizes, int n_in,
                              void* d_out, int out_size, void* d_ws, size_t ws_size,
                              hipStream_t stream) {
    const float* boxes  = (const float*)d_in[0];
    const float* scores = (const float*)d_in[1];
    const int*   labels = (const int*)d_in[2];
    float* out = (float*)d_out;
    (void)in_sizes; (void)n_in; (void)out_size; (void)ws_size;
    softnms_fused<<<2, T, 0, stream>>>(boxes, scores, labels, d_ws);
    softnms_merge<<<N_BOXES / 256, 256, 0, stream>>>(d_ws, out);
}

// Round 9
// 2615.279 us; speedup vs baseline: 1.9563x; 1.0301x over previous
//
#include <hip/hip_runtime.h>
#include <stdint.h>

// SoftNMS (gaussian, sigma=0.5, thr=0.001), N=4096, 2 classes.
// R15: PAIRING ON THE PROVEN R12 REPLAY. R13/R14 hung: replay pulled
// lane-resident winners via readlane/__shfl with a DIVERGENT index inside the
// bit-walk loop; ds_bpermute does not return valid data from EXEC=0 lanes
// (threads that already exited the walk), so wst was garbage -> winner never
// zeroed -> livelock. Fix: batch winners return to LDS (batchbox/batchstat,
// tid0-written, B2-protected) and replay is R12's per-thread bit-walk with
// divergent LDS reads (well-defined; R12 measured 2694us, absmax 0.0).
// R13's paired selections are kept in the sim: after winner1, the masked
// runner-up is provably the next serial winner iff its box is disjoint from
// winner1's (others <= it pre-decay; decay only shrinks; disjoint => bitwise
// untouched; every ranking-affecting case is declined by the overlap check).
// d1,d2 decay chains run ILP-parallel; applied sc*d1(kill)*d2(kill) = serial.
// HANG-PROOFING (never fires if correct): outer loop capped, staging writes
// bounds-guarded, flush/count clamped -> a logic flaw now yields finite wrong
// output (absmax signal) instead of a timeout.

#define N_BOXES 4096
#define T 256
#define CAP 16            // slots/thread capacity (worst case: one class owns all)
#define BOXCAP 2560       // LDS cache capacity (40KB box + 20KB key)
#define SCORE_THR 0.001f
#define BMAX 32           // batch cap (u32 hit-bitmask width)

typedef unsigned long long u64;
typedef uint32_t u32;

__device__ __forceinline__ u64 kmax(u64 a, u64 b) { return a > b ? a : b; }
__device__ __forceinline__ u64 kmin(u64 a, u64 b) { return a < b ? a : b; }

// LLVM gfx9 wave64 reduction sequence; identity 0, inputs non-negative.
__device__ __forceinline__ int wave_max_nonneg(int v) {
    v = max(v, __builtin_amdgcn_update_dpp(0, v, 0x111, 0xf, 0xf, false)); // row_shr:1
    v = max(v, __builtin_amdgcn_update_dpp(0, v, 0x112, 0xf, 0xf, false)); // row_shr:2
    v = max(v, __builtin_amdgcn_update_dpp(0, v, 0x114, 0xf, 0xf, false)); // row_shr:4
    v = max(v, __builtin_amdgcn_update_dpp(0, v, 0x118, 0xf, 0xf, false)); // row_shr:8
    v = max(v, __builtin_amdgcn_update_dpp(0, v, 0x142, 0xa, 0xf, false)); // row_bcast:15
    v = max(v, __builtin_amdgcn_update_dpp(0, v, 0x143, 0xc, 0xf, false)); // row_bcast:31
    return __builtin_amdgcn_readlane(v, 63);
}

// exact u64 wave max, two-phase (score bits then tie-break bits).
__device__ __forceinline__ u64 wave_max_u64(u64 x) {
    int hi   = (int)(u32)(x >> 32);
    int hmax = wave_max_nonneg(hi);
    int lom  = (hi == hmax) ? (int)(u32)x : 0;
    int lmax = wave_max_nonneg(lom);
    return ((u64)(u32)hmax << 32) | (u64)(u32)lmax;
}

// uniform-index broadcast (v_readlane; index wave-uniform, all lanes active)
__device__ __forceinline__ float readlane_f(float v, int l) {
    return __uint_as_float((u32)__builtin_amdgcn_readlane((int)__float_as_uint(v), l));
}

// workspace layout (196624 bytes)
#define WS_KEY(ws, c)  ((u64*)((char*)(ws) + (size_t)(c) * 32768))
#define WS_BOX(ws, c)  ((float4*)((char*)(ws) + 65536 + (size_t)(c) * 65536))
#define WS_CNT(ws)     ((int*)((char*)(ws) + 196608))

__launch_bounds__(T, 1)
__global__ void softnms_fused(const float* __restrict__ boxes,
                              const float* __restrict__ scores,
                              const int* __restrict__ labels,
                              void* __restrict__ ws) {
    const int cls  = blockIdx.x;
    const int tid  = threadIdx.x;
    const int lane = tid & 63;
    const int wid  = tid >> 6;

    __shared__ u64    maskw[64];          // class-membership bitmask
    __shared__ u32    wordpref[64];       // inclusive prefix of popcounts
    __shared__ u64    redG[4];            // per-wave max of per-thread 2nd key
    __shared__ u64    cand[T];            // per-thread m1 posting (256)
    __shared__ float4 batchbox[BMAX];     // winner boxes of current batch
    __shared__ u32    batchstat[BMAX];    // winner statics of current batch
    __shared__ float4 box_lds[BOXCAP];
    __shared__ u64    okey_lds[BOXCAP];

    // ---- phase 0a: membership bitmask + popcount prefix ----
    for (int base = 0; base < N_BOXES; base += T) {
        u64 bal = __ballot(labels[base + tid] == cls);
        if (lane == 0) maskw[(base >> 6) + wid] = bal;
    }
    __syncthreads();
    if (wid == 0) {
        u32 v = (u32)__popcll(maskw[lane]);
        #pragma unroll
        for (int d = 1; d < 64; d <<= 1) {
            u32 o = __shfl_up(v, d, 64);
            if (lane >= d) v += o;
        }
        wordpref[lane] = v;
    }
    __syncthreads();
    const int cnt = __builtin_amdgcn_readfirstlane((int)wordpref[63]);

    // ---- phase 0b: rank-select my slots (r = tid + 256*j) -> regs + LDS ----
    float x1r[CAP], y1r[CAP], x2r[CAP], y2r[CAP], ar[CAP];
    u64 key[CAP];
    const float4* boxes4 = reinterpret_cast<const float4*>(boxes);
    #pragma unroll
    for (int j = 0; j < CAP; ++j) {
        key[j] = 0;
        x1r[j] = 0.0f; y1r[j] = 0.0f; x2r[j] = 0.0f; y2r[j] = 0.0f; ar[j] = 0.0f;
        int r = tid + T * j;
        if (r < cnt) {
            int lo = 0, hi = 63;   // smallest word W with wordpref[W] > r
            while (lo < hi) { int mid = (lo + hi) >> 1; if (wordpref[mid] > (u32)r) hi = mid; else lo = mid + 1; }
            int W = lo;
            u32 rb = (W == 0) ? 0u : wordpref[W - 1];
            u32 t = (u32)r - rb;
            u64 x = maskw[W];
            int pos = 0;
            u32 c;
            c = (u32)__popcll(x & 0xFFFFFFFFull); if (t >= c) { pos += 32; t -= c; x >>= 32; }
            c = (u32)__popcll(x & 0xFFFFull);     if (t >= c) { pos += 16; t -= c; x >>= 16; }
            c = (u32)__popcll(x & 0xFFull);       if (t >= c) { pos += 8;  t -= c; x >>= 8; }
            c = (u32)__popcll(x & 0xFull);        if (t >= c) { pos += 4;  t -= c; x >>= 4; }
            c = (u32)__popcll(x & 0x3ull);        if (t >= c) { pos += 2;  t -= c; x >>= 2; }
            c = (u32)__popcll(x & 0x1ull);        if (t >= c) { pos += 1; }
            int g = W * 64 + pos;
            float4 b = boxes4[g];
            x1r[j] = b.x; y1r[j] = b.y; x2r[j] = b.z; y2r[j] = b.w;
            ar[j]  = __fmul_rn(__fsub_rn(b.z, b.x), __fsub_rn(b.w, b.y));
            float s = scores[g];
            // key: score<<32 | (4095-g)<<16 | r   (g: argmax tie-break; r: slot)
            key[j] = ((u64)__float_as_uint(s) << 32)
                   | ((u64)(u32)(4095 - g) << 16) | (u64)(u32)r;
            if (r < BOXCAP) box_lds[r] = b;
        }
    }
    __syncthreads();

    // ---- phase 1: guarded batch simulation, paired selections ----
    u64*    okey = WS_KEY(ws, cls);
    float4* obox = WS_BOX(ws, cls);
    const bool use_lds = (cnt <= BOXCAP);
    int mcnt = 0;

    for (int outer = 0; outer <= N_BOXES; ++outer) {   // cap: insurance only
        // gather: per-thread top-2 of live keys (u64, branchless)
        u64 m1 = 0, m2 = 0;
        #pragma unroll
        for (int j = 0; j < CAP; ++j) {
            if (T * j < cnt) {
                u64 kj  = key[j];
                u64 nm1 = kmax(m1, kj);
                m2 = kmax(m2, kmin(m1, kj));
                m1 = nm1;
            }
        }
        u64 wg = wave_max_u64(m2);
        if (lane == 0) redG[wid] = wg;
        cand[tid] = m1;
        __syncthreads();                               // B1: posts visible

        // level-2: lane keeps only its max of 4 candidates; 2nd folds into G
        u64 c1 = 0, c2 = 0;
        #pragma unroll
        for (int q = 0; q < 4; ++q) {
            u64 c  = cand[lane + 64 * q];
            u64 n1 = kmax(c1, c);
            c2 = kmax(c2, kmin(c1, c));
            c1 = n1;
        }
        u64 G = kmax(kmax(kmax(redG[0], redG[1]), kmax(redG[2], redG[3])),
                     wave_max_u64(c2));
        const u32 Ghi = (u32)(G >> 32), Glo = (u32)G;

        u32 cscb = (u32)(c1 >> 32);                    // score bits (non-neg)
        u32 cst  = (u32)c1;                            // static (unique)
        float4 cb;
        if (use_lds) cb = box_lds[(int)(c1 & 0xFFFF)];
        else         cb = boxes4[4095 - (int)((c1 >> 16) & 0xFFFF)];
        float car = __fmul_rn(__fsub_rn(cb.z, cb.x), __fsub_rn(cb.w, cb.y));

        u32 hm[CAP];                                   // per-slot hit bitmasks
        #pragma unroll
        for (int j = 0; j < CAP; ++j) hm[j] = 0;

        int did = 0;
        for (;;) {
            // ---- winner 1: wave argmax on score bits (tie path rare) ----
            int h1 = wave_max_nonneg((int)cscb);
            const u32 uh1 = (u32)h1;
            if (uh1 == 0u) break;                      // all dead
            if (uh1 < Ghi) break;                      // guard (fast)
            u64 b1m = __ballot(cscb == uh1);
            u32 ul1; int src1;
            if (__popcll(b1m) == 1) {
                src1 = (int)__builtin_ctzll(b1m);
                ul1  = (u32)__builtin_amdgcn_readlane((int)cst, src1);
            } else {
                int lom = (cscb == uh1) ? (int)cst : 0;
                ul1 = (u32)wave_max_nonneg(lom);
                src1 = (int)__builtin_ctzll(__ballot((cscb == uh1) & (cst == ul1)));
            }
            if (uh1 == Ghi && ul1 <= Glo) break;       // guard (exact)
            if (did == BMAX) break;                    // mask width

            float w1x1 = readlane_f(cb.x, src1);
            float w1y1 = readlane_f(cb.y, src1);
            float w1x2 = readlane_f(cb.z, src1);
            float w1y2 = readlane_f(cb.w, src1);
            float war1 = readlane_f(car,  src1);

            // ---- winner 2 (speculative): masked runner-up ----
            u32 csc2 = (lane == src1) ? 0u : cscb;
            int h2 = wave_max_nonneg((int)csc2);
            const u32 uh2 = (u32)h2;
            bool take2 = false; int src2 = 0; u32 ul2 = 0;
            float w2x1 = 0.0f, w2y1 = 0.0f, w2x2 = 0.0f, w2y2 = 0.0f, war2 = 0.0f;
            if (uh2 != 0u && uh2 >= Ghi && (did + 1) < BMAX) {
                u64 b2m = __ballot(csc2 == uh2);
                if (__popcll(b2m) == 1) {
                    src2 = (int)__builtin_ctzll(b2m);
                    ul2  = (u32)__builtin_amdgcn_readlane((int)cst, src2);
                } else {
                    int lom2 = (csc2 == uh2) ? (int)cst : 0;
                    ul2 = (u32)wave_max_nonneg(lom2);
                    src2 = (int)__builtin_ctzll(__ballot((csc2 == uh2) & (cst == ul2)));
                }
                if (uh2 > Ghi || ul2 > Glo) {
                    w2x1 = readlane_f(cb.x, src2);
                    w2y1 = readlane_f(cb.y, src2);
                    w2x2 = readlane_f(cb.z, src2);
                    w2y2 = readlane_f(cb.w, src2);
                    war2 = readlane_f(car,  src2);
                    // pair valid iff boxes disjoint (covers all ranking-change cases)
                    bool ovl = (w1x2 > w2x1) & (w2x2 > w1x1)
                             & (w1y2 > w2y1) & (w2y2 > w1y1);
                    take2 = !ovl;
                }
            }

            // ---- stage winners: LDS batch arrays + output keys (tid0) ----
            if (tid == 0) {
                u64 w1k = ((u64)uh1 << 32) | (u64)ul1;
                batchbox[did]  = make_float4(w1x1, w1y1, w1x2, w1y2);
                batchstat[did] = ul1;
                if (use_lds) { if (mcnt < BOXCAP) okey_lds[mcnt] = w1k; }
                else if (mcnt < N_BOXES) { okey[mcnt] = w1k; obox[mcnt] = make_float4(w1x1, w1y1, w1x2, w1y2); }
                if (take2) {
                    u64 w2k = ((u64)uh2 << 32) | (u64)ul2;
                    batchbox[did + 1]  = make_float4(w2x1, w2y1, w2x2, w2y2);
                    batchstat[did + 1] = ul2;
                    if (use_lds) { if (mcnt + 1 < BOXCAP) okey_lds[mcnt + 1] = w2k; }
                    else if (mcnt + 1 < N_BOXES) { okey[mcnt + 1] = w2k; obox[mcnt + 1] = make_float4(w2x1, w2y1, w2x2, w2y2); }
                }
            }

            // ---- candidate decay: d1 (and d2) chains ILP-parallel, applied in order ----
            float i1x1 = fmaxf(w1x1, cb.x);
            float i1y1 = fmaxf(w1y1, cb.y);
            float i1x2 = fminf(w1x2, cb.z);
            float i1y2 = fminf(w1y2, cb.w);
            float iw1  = fmaxf(__fsub_rn(i1x2, i1x1), 0.0f);
            float ih1  = fmaxf(__fsub_rn(i1y2, i1y1), 0.0f);
            float int1 = __fmul_rn(iw1, ih1);
            float den1 = __fadd_rn(__fsub_rn(__fadd_rn(war1, car), int1), 1e-8f);
            float iou1 = int1 / den1;                    // IEEE div
            float d1   = expf(__fmul_rn(-2.0f, __fmul_rn(iou1, iou1)));

            float s0 = __uint_as_float(cscb);
            float n1 = __fmul_rn(s0, d1);
            float k1 = (n1 >= SCORE_THR) ? n1 : 0.0f;
            float a1 = (int1 > 0.0f) ? k1 : s0;
            a1 = (lane == src1) ? 0.0f : a1;
            float res = a1;

            if (take2) {
                float i2x1 = fmaxf(w2x1, cb.x);
                float i2y1 = fmaxf(w2y1, cb.y);
                float i2x2 = fminf(w2x2, cb.z);
                float i2y2 = fminf(w2y2, cb.w);
                float iw2  = fmaxf(__fsub_rn(i2x2, i2x1), 0.0f);
                float ih2  = fmaxf(__fsub_rn(i2y2, i2y1), 0.0f);
                float int2 = __fmul_rn(iw2, ih2);
                float den2 = __fadd_rn(__fsub_rn(__fadd_rn(war2, car), int2), 1e-8f);
                float iou2 = int2 / den2;                // IEEE div
                float d2   = expf(__fmul_rn(-2.0f, __fmul_rn(iou2, iou2)));
                float n2 = __fmul_rn(a1, d2);
                float k2 = (n2 >= SCORE_THR) ? n2 : 0.0f;
                float a2 = (int2 > 0.0f) ? k2 : a1;
                res = (lane == src2) ? 0.0f : a2;
            }
            cscb = __float_as_uint(res);

            // ---- owned-slot hit bits (bodies deferred to replay) ----
            u32 bit1 = 1u << did;
            u32 bit2 = (take2 ? (2u << did) : 0u);
            #pragma unroll
            for (int j = 0; j < CAP; ++j) {
                if (T * j < cnt) {
                    bool hit1 = (w1x2 > x1r[j]) & (x2r[j] > w1x1)
                              & (w1y2 > y1r[j]) & (y2r[j] > w1y1);
                    u32 h = hit1 ? bit1 : 0u;
                    if (take2) {
                        bool hit2 = (w2x2 > x1r[j]) & (x2r[j] > w2x1)
                                  & (w2y2 > y1r[j]) & (y2r[j] > w2y1);
                        h |= hit2 ? bit2 : 0u;
                    }
                    hm[j] |= h;
                }
            }
            int adv = take2 ? 2 : 1;
            mcnt += adv; did += adv;
        }
        if (did == 0) break;                           // all keys dead
        __syncthreads();                               // B2: batch arrays visible

        // ---- replay: full exact body on set bits, ascending batch order ----
        // divergent LDS reads (well-defined), R12-proven structure
        #pragma unroll
        for (int j = 0; j < CAP; ++j) {
            if (T * j < cnt) {
                u32 m = hm[j];
                while (m) {
                    int b = (int)__builtin_ctz(m);
                    m &= (m - 1);
                    float4 wb = batchbox[b];
                    u32   wst = batchstat[b];
                    float wx1 = wb.x, wy1 = wb.y, wx2 = wb.z, wy2 = wb.w;
                    float warea = __fmul_rn(__fsub_rn(wx2, wx1), __fsub_rn(wy2, wy1));
                    u64 kj = key[j];
                    float ix1   = fmaxf(wx1, x1r[j]);
                    float iy1   = fmaxf(wy1, y1r[j]);
                    float ix2   = fminf(wx2, x2r[j]);
                    float iy2   = fminf(wy2, y2r[j]);
                    float iw    = fmaxf(__fsub_rn(ix2, ix1), 0.0f);
                    float ih    = fmaxf(__fsub_rn(iy2, iy1), 0.0f);
                    float inter = __fmul_rn(iw, ih);
                    float denom = __fadd_rn(__fsub_rn(__fadd_rn(warea, ar[j]), inter), 1e-8f);
                    float iou   = inter / denom;                // IEEE div
                    float t2    = __fmul_rn(iou, iou);
                    float decay = expf(__fmul_rn(-2.0f, t2));   // exp(-iou^2/0.5)
                    float sc    = __uint_as_float((u32)(kj >> 32));
                    float ns    = __fmul_rn(sc, decay);
                    bool  app   = (kj != 0) && (inter > 0.0f);
                    u64   nk    = ((u64)__float_as_uint(ns) << 32) | (kj & 0xFFFFFFFFull);
                    u64   upd   = app ? ((ns >= SCORE_THR) ? nk : 0ull) : kj;
                    key[j] = ((u32)kj == wst) ? 0ull : upd;     // winner-zero (static unique)
                }
            }
        }
    }

    // ---- batched flush of staged winners (boxes recovered by rank) ----
    int mfin = (mcnt <= cnt) ? mcnt : cnt;             // clamp: insurance only
    if (use_lds) {
        __syncthreads();
        int fl = (mfin <= BOXCAP) ? mfin : BOXCAP;
        for (int m = tid; m < fl; m += T) {
            u64 w = okey_lds[m];
            okey[m] = w;
            obox[m] = box_lds[(int)(w & 0xFFFF)];
        }
    }
    if (tid == 0) WS_CNT(ws)[cls] = mfin;
}

// merge the two strictly-descending key lists by rank; pad the tail
__global__ void softnms_merge(void* __restrict__ ws, float* __restrict__ out) {
    int k = blockIdx.x * blockDim.x + threadIdx.x;   // 0..4095
    const u64*    keyA = WS_KEY(ws, 0);
    const u64*    keyB = WS_KEY(ws, 1);
    const float4* boxA = WS_BOX(ws, 0);
    const float4* boxB = WS_BOX(ws, 1);
    const int mA = WS_CNT(ws)[0];
    const int mB = WS_CNT(ws)[1];

    float* ob = out;
    float* os = out + N_BOXES * 4;
    float* ol = out + N_BOXES * 5;

    if (k < mA) {
        u64 x = keyA[k];
        int lo = 0, hi = mB;
        while (lo < hi) { int mid = (lo + hi) >> 1; if (keyB[mid] > x) lo = mid + 1; else hi = mid; }
        int pos = k + lo;
        float4 b = boxA[k];
        ob[pos * 4 + 0] = b.x; ob[pos * 4 + 1] = b.y;
        ob[pos * 4 + 2] = b.z; ob[pos * 4 + 3] = b.w;
        os[pos] = __uint_as_float((u32)(x >> 32));
        ol[pos] = 0.0f;
    } else if (k < mA + mB) {
        int i = k - mA;
        u64 x = keyB[i];
        int lo = 0, hi = mA;
        while (lo < hi) { int mid = (lo + hi) >> 1; if (keyA[mid] > x) lo = mid + 1; else hi = mid; }
        int pos = i + lo;
        float4 b = boxB[i];
        ob[pos * 4 + 0] = b.x; ob[pos * 4 + 1] = b.y;
        ob[pos * 4 + 2] = b.z; ob[pos * 4 + 3] = b.w;
        os[pos] = __uint_as_float((u32)(x >> 32));
        ol[pos] = 1.0f;
    } else {
        ob[k * 4 + 0] = 0.0f; ob[k * 4 + 1] = 0.0f;
        ob[k * 4 + 2] = 0.0f; ob[k * 4 + 3] = 0.0f;
        os[k] = 0.0f;
        ol[k] = -1.0f;
    }
}

extern "C" void kernel_launch(void* const* d_in, const int* in_sizes, int n_in,
                              void* d_out, int out_size, void* d_ws, size_t ws_size,
                              hipStream_t stream) {
    const float* boxes  = (const float*)d_in[0];
    const float* scores = (const float*)d_in[1];
    const int*   labels = (const int*)d_in[2];
    float* out = (float*)d_out;
    (void)in_sizes; (void)n_in; (void)out_size; (void)ws_size;
    softnms_fused<<<2, T, 0, stream>>>(boxes, scores, labels, d_ws);
    softnms_merge<<<N_BOXES / 256, 256, 0, stream>>>(d_ws, out);
}

// Round 10
// 2037.659 us; speedup vs baseline: 2.5109x; 1.2835x over previous
//
#include <hip/hip_runtime.h>
#include <stdint.h>

// SoftNMS (gaussian, sigma=0.5, thr=0.001), N=4096, 2 classes.
// R16: 2 WAVES PER SIMD (T=256 -> 512). R15's pairing bought only 3% =>
// cost scales with per-selection WORK, not chain count; at 1 wave/SIMD the
// ~70% non-VALU share (SALU, branches, exec-mask ops, DPP/div/exp latency
// holes) is unfilled issue slots. Fix: T=512 (8 waves, 2/SIMD) so a second
// wave fills the holes. Sim is redundant per wave (no extra critical-path
// work); slots/thread halves (CAP 16->8) so hit-test+replay per wave halves.
// Mechanical re-parameterization: cand[512], lane-fold 8/lane (guard proof
// unchanged), redG[8]. Pairing, replay, kill rule byte-identical (R15-
// verified, absmax 0.0). Hang insurance retained.

#define N_BOXES 4096
#define T 512
#define NWAVE (T / 64)
#define CAP 8             // slots/thread capacity (worst case: one class owns all)
#define FOLD (T / 64)     // candidates folded per lane (8)
#define BOXCAP 2560       // LDS cache capacity (40KB box + 20KB key)
#define SCORE_THR 0.001f
#define BMAX 32           // batch cap (u32 hit-bitmask width)

typedef unsigned long long u64;
typedef uint32_t u32;

__device__ __forceinline__ u64 kmax(u64 a, u64 b) { return a > b ? a : b; }
__device__ __forceinline__ u64 kmin(u64 a, u64 b) { return a < b ? a : b; }

// LLVM gfx9 wave64 reduction sequence; identity 0, inputs non-negative.
__device__ __forceinline__ int wave_max_nonneg(int v) {
    v = max(v, __builtin_amdgcn_update_dpp(0, v, 0x111, 0xf, 0xf, false)); // row_shr:1
    v = max(v, __builtin_amdgcn_update_dpp(0, v, 0x112, 0xf, 0xf, false)); // row_shr:2
    v = max(v, __builtin_amdgcn_update_dpp(0, v, 0x114, 0xf, 0xf, false)); // row_shr:4
    v = max(v, __builtin_amdgcn_update_dpp(0, v, 0x118, 0xf, 0xf, false)); // row_shr:8
    v = max(v, __builtin_amdgcn_update_dpp(0, v, 0x142, 0xa, 0xf, false)); // row_bcast:15
    v = max(v, __builtin_amdgcn_update_dpp(0, v, 0x143, 0xc, 0xf, false)); // row_bcast:31
    return __builtin_amdgcn_readlane(v, 63);
}

// exact u64 wave max, two-phase (score bits then tie-break bits).
__device__ __forceinline__ u64 wave_max_u64(u64 x) {
    int hi   = (int)(u32)(x >> 32);
    int hmax = wave_max_nonneg(hi);
    int lom  = (hi == hmax) ? (int)(u32)x : 0;
    int lmax = wave_max_nonneg(lom);
    return ((u64)(u32)hmax << 32) | (u64)(u32)lmax;
}

// uniform-index broadcast (v_readlane; index wave-uniform, all lanes active)
__device__ __forceinline__ float readlane_f(float v, int l) {
    return __uint_as_float((u32)__builtin_amdgcn_readlane((int)__float_as_uint(v), l));
}

// workspace layout (196624 bytes)
#define WS_KEY(ws, c)  ((u64*)((char*)(ws) + (size_t)(c) * 32768))
#define WS_BOX(ws, c)  ((float4*)((char*)(ws) + 65536 + (size_t)(c) * 65536))
#define WS_CNT(ws)     ((int*)((char*)(ws) + 196608))

__launch_bounds__(T, 1)
__global__ void softnms_fused(const float* __restrict__ boxes,
                              const float* __restrict__ scores,
                              const int* __restrict__ labels,
                              void* __restrict__ ws) {
    const int cls  = blockIdx.x;
    const int tid  = threadIdx.x;
    const int lane = tid & 63;
    const int wid  = tid >> 6;

    __shared__ u64    maskw[64];          // class-membership bitmask
    __shared__ u32    wordpref[64];       // inclusive prefix of popcounts
    __shared__ u64    redG[NWAVE];        // per-wave max of per-thread 2nd key
    __shared__ u64    cand[T];            // per-thread m1 posting (512)
    __shared__ float4 batchbox[BMAX];     // winner boxes of current batch
    __shared__ u32    batchstat[BMAX];    // winner statics of current batch
    __shared__ float4 box_lds[BOXCAP];
    __shared__ u64    okey_lds[BOXCAP];

    // ---- phase 0a: membership bitmask + popcount prefix ----
    for (int base = 0; base < N_BOXES; base += T) {
        u64 bal = __ballot(labels[base + tid] == cls);
        if (lane == 0) maskw[(base >> 6) + wid] = bal;
    }
    __syncthreads();
    if (wid == 0) {
        u32 v = (u32)__popcll(maskw[lane]);
        #pragma unroll
        for (int d = 1; d < 64; d <<= 1) {
            u32 o = __shfl_up(v, d, 64);
            if (lane >= d) v += o;
        }
        wordpref[lane] = v;
    }
    __syncthreads();
    const int cnt = __builtin_amdgcn_readfirstlane((int)wordpref[63]);

    // ---- phase 0b: rank-select my slots (r = tid + T*j) -> regs + LDS ----
    float x1r[CAP], y1r[CAP], x2r[CAP], y2r[CAP], ar[CAP];
    u64 key[CAP];
    const float4* boxes4 = reinterpret_cast<const float4*>(boxes);
    #pragma unroll
    for (int j = 0; j < CAP; ++j) {
        key[j] = 0;
        x1r[j] = 0.0f; y1r[j] = 0.0f; x2r[j] = 0.0f; y2r[j] = 0.0f; ar[j] = 0.0f;
        int r = tid + T * j;
        if (r < cnt) {
            int lo = 0, hi = 63;   // smallest word W with wordpref[W] > r
            while (lo < hi) { int mid = (lo + hi) >> 1; if (wordpref[mid] > (u32)r) hi = mid; else lo = mid + 1; }
            int W = lo;
            u32 rb = (W == 0) ? 0u : wordpref[W - 1];
            u32 t = (u32)r - rb;
            u64 x = maskw[W];
            int pos = 0;
            u32 c;
            c = (u32)__popcll(x & 0xFFFFFFFFull); if (t >= c) { pos += 32; t -= c; x >>= 32; }
            c = (u32)__popcll(x & 0xFFFFull);     if (t >= c) { pos += 16; t -= c; x >>= 16; }
            c = (u32)__popcll(x & 0xFFull);       if (t >= c) { pos += 8;  t -= c; x >>= 8; }
            c = (u32)__popcll(x & 0xFull);        if (t >= c) { pos += 4;  t -= c; x >>= 4; }
            c = (u32)__popcll(x & 0x3ull);        if (t >= c) { pos += 2;  t -= c; x >>= 2; }
            c = (u32)__popcll(x & 0x1ull);        if (t >= c) { pos += 1; }
            int g = W * 64 + pos;
            float4 b = boxes4[g];
            x1r[j] = b.x; y1r[j] = b.y; x2r[j] = b.z; y2r[j] = b.w;
            ar[j]  = __fmul_rn(__fsub_rn(b.z, b.x), __fsub_rn(b.w, b.y));
            float s = scores[g];
            // key: score<<32 | (4095-g)<<16 | r   (g: argmax tie-break; r: slot)
            key[j] = ((u64)__float_as_uint(s) << 32)
                   | ((u64)(u32)(4095 - g) << 16) | (u64)(u32)r;
            if (r < BOXCAP) box_lds[r] = b;
        }
    }
    __syncthreads();

    // ---- phase 1: guarded batch simulation, paired selections ----
    u64*    okey = WS_KEY(ws, cls);
    float4* obox = WS_BOX(ws, cls);
    const bool use_lds = (cnt <= BOXCAP);
    int mcnt = 0;

    for (int outer = 0; outer <= N_BOXES; ++outer) {   // cap: insurance only
        // gather: per-thread top-2 of live keys (u64, branchless)
        u64 m1 = 0, m2 = 0;
        #pragma unroll
        for (int j = 0; j < CAP; ++j) {
            if (T * j < cnt) {
                u64 kj  = key[j];
                u64 nm1 = kmax(m1, kj);
                m2 = kmax(m2, kmin(m1, kj));
                m1 = nm1;
            }
        }
        u64 wg = wave_max_u64(m2);
        if (lane == 0) redG[wid] = wg;
        cand[tid] = m1;
        __syncthreads();                               // B1: posts visible

        // level-2: lane keeps only its max of FOLD candidates; 2nd folds into G
        u64 c1 = 0, c2 = 0;
        #pragma unroll
        for (int q = 0; q < FOLD; ++q) {
            u64 c  = cand[lane + 64 * q];
            u64 n1 = kmax(c1, c);
            c2 = kmax(c2, kmin(c1, c));
            c1 = n1;
        }
        u64 Gr = redG[0];
        #pragma unroll
        for (int q = 1; q < NWAVE; ++q) Gr = kmax(Gr, redG[q]);
        u64 G = kmax(Gr, wave_max_u64(c2));
        const u32 Ghi = (u32)(G >> 32), Glo = (u32)G;

        u32 cscb = (u32)(c1 >> 32);                    // score bits (non-neg)
        u32 cst  = (u32)c1;                            // static (unique)
        float4 cb;
        if (use_lds) cb = box_lds[(int)(c1 & 0xFFFF)];
        else         cb = boxes4[4095 - (int)((c1 >> 16) & 0xFFFF)];
        float car = __fmul_rn(__fsub_rn(cb.z, cb.x), __fsub_rn(cb.w, cb.y));

        u32 hm[CAP];                                   // per-slot hit bitmasks
        #pragma unroll
        for (int j = 0; j < CAP; ++j) hm[j] = 0;

        int did = 0;
        for (;;) {
            // ---- winner 1: wave argmax on score bits (tie path rare) ----
            int h1 = wave_max_nonneg((int)cscb);
            const u32 uh1 = (u32)h1;
            if (uh1 == 0u) break;                      // all dead
            if (uh1 < Ghi) break;                      // guard (fast)
            u64 b1m = __ballot(cscb == uh1);
            u32 ul1; int src1;
            if (__popcll(b1m) == 1) {
                src1 = (int)__builtin_ctzll(b1m);
                ul1  = (u32)__builtin_amdgcn_readlane((int)cst, src1);
            } else {
                int lom = (cscb == uh1) ? (int)cst : 0;
                ul1 = (u32)wave_max_nonneg(lom);
                src1 = (int)__builtin_ctzll(__ballot((cscb == uh1) & (cst == ul1)));
            }
            if (uh1 == Ghi && ul1 <= Glo) break;       // guard (exact)
            if (did == BMAX) break;                    // mask width

            float w1x1 = readlane_f(cb.x, src1);
            float w1y1 = readlane_f(cb.y, src1);
            float w1x2 = readlane_f(cb.z, src1);
            float w1y2 = readlane_f(cb.w, src1);
            float war1 = readlane_f(car,  src1);

            // ---- winner 2 (speculative): masked runner-up ----
            u32 csc2 = (lane == src1) ? 0u : cscb;
            int h2 = wave_max_nonneg((int)csc2);
            const u32 uh2 = (u32)h2;
            bool take2 = false; int src2 = 0; u32 ul2 = 0;
            float w2x1 = 0.0f, w2y1 = 0.0f, w2x2 = 0.0f, w2y2 = 0.0f, war2 = 0.0f;
            if (uh2 != 0u && uh2 >= Ghi && (did + 1) < BMAX) {
                u64 b2m = __ballot(csc2 == uh2);
                if (__popcll(b2m) == 1) {
                    src2 = (int)__builtin_ctzll(b2m);
                    ul2  = (u32)__builtin_amdgcn_readlane((int)cst, src2);
                } else {
                    int lom2 = (csc2 == uh2) ? (int)cst : 0;
                    ul2 = (u32)wave_max_nonneg(lom2);
                    src2 = (int)__builtin_ctzll(__ballot((csc2 == uh2) & (cst == ul2)));
                }
                if (uh2 > Ghi || ul2 > Glo) {
                    w2x1 = readlane_f(cb.x, src2);
                    w2y1 = readlane_f(cb.y, src2);
                    w2x2 = readlane_f(cb.z, src2);
                    w2y2 = readlane_f(cb.w, src2);
                    war2 = readlane_f(car,  src2);
                    // pair valid iff boxes disjoint (covers all ranking-change cases)
                    bool ovl = (w1x2 > w2x1) & (w2x2 > w1x1)
                             & (w1y2 > w2y1) & (w2y2 > w1y1);
                    take2 = !ovl;
                }
            }

            // ---- stage winners: LDS batch arrays + output keys (tid0) ----
            if (tid == 0) {
                u64 w1k = ((u64)uh1 << 32) | (u64)ul1;
                batchbox[did]  = make_float4(w1x1, w1y1, w1x2, w1y2);
                batchstat[did] = ul1;
                if (use_lds) { if (mcnt < BOXCAP) okey_lds[mcnt] = w1k; }
                else if (mcnt < N_BOXES) { okey[mcnt] = w1k; obox[mcnt] = make_float4(w1x1, w1y1, w1x2, w1y2); }
                if (take2) {
                    u64 w2k = ((u64)uh2 << 32) | (u64)ul2;
                    batchbox[did + 1]  = make_float4(w2x1, w2y1, w2x2, w2y2);
                    batchstat[did + 1] = ul2;
                    if (use_lds) { if (mcnt + 1 < BOXCAP) okey_lds[mcnt + 1] = w2k; }
                    else if (mcnt + 1 < N_BOXES) { okey[mcnt + 1] = w2k; obox[mcnt + 1] = make_float4(w2x1, w2y1, w2x2, w2y2); }
                }
            }

            // ---- candidate decay: d1 (and d2) chains ILP-parallel, applied in order ----
            float i1x1 = fmaxf(w1x1, cb.x);
            float i1y1 = fmaxf(w1y1, cb.y);
            float i1x2 = fminf(w1x2, cb.z);
            float i1y2 = fminf(w1y2, cb.w);
            float iw1  = fmaxf(__fsub_rn(i1x2, i1x1), 0.0f);
            float ih1  = fmaxf(__fsub_rn(i1y2, i1y1), 0.0f);
            float int1 = __fmul_rn(iw1, ih1);
            float den1 = __fadd_rn(__fsub_rn(__fadd_rn(war1, car), int1), 1e-8f);
            float iou1 = int1 / den1;                    // IEEE div
            float d1   = expf(__fmul_rn(-2.0f, __fmul_rn(iou1, iou1)));

            float s0 = __uint_as_float(cscb);
            float n1 = __fmul_rn(s0, d1);
            float k1 = (n1 >= SCORE_THR) ? n1 : 0.0f;
            float a1 = (int1 > 0.0f) ? k1 : s0;
            a1 = (lane == src1) ? 0.0f : a1;
            float res = a1;

            if (take2) {
                float i2x1 = fmaxf(w2x1, cb.x);
                float i2y1 = fmaxf(w2y1, cb.y);
                float i2x2 = fminf(w2x2, cb.z);
                float i2y2 = fminf(w2y2, cb.w);
                float iw2  = fmaxf(__fsub_rn(i2x2, i2x1), 0.0f);
                float ih2  = fmaxf(__fsub_rn(i2y2, i2y1), 0.0f);
                float int2 = __fmul_rn(iw2, ih2);
                float den2 = __fadd_rn(__fsub_rn(__fadd_rn(war2, car), int2), 1e-8f);
                float iou2 = int2 / den2;                // IEEE div
                float d2   = expf(__fmul_rn(-2.0f, __fmul_rn(iou2, iou2)));
                float n2 = __fmul_rn(a1, d2);
                float k2 = (n2 >= SCORE_THR) ? n2 : 0.0f;
                float a2 = (int2 > 0.0f) ? k2 : a1;
                res = (lane == src2) ? 0.0f : a2;
            }
            cscb = __float_as_uint(res);

            // ---- owned-slot hit bits (bodies deferred to replay) ----
            u32 bit1 = 1u << did;
            u32 bit2 = (take2 ? (2u << did) : 0u);
            #pragma unroll
            for (int j = 0; j < CAP; ++j) {
                if (T * j < cnt) {
                    bool hit1 = (w1x2 > x1r[j]) & (x2r[j] > w1x1)
                              & (w1y2 > y1r[j]) & (y2r[j] > w1y1);
                    u32 h = hit1 ? bit1 : 0u;
                    if (take2) {
                        bool hit2 = (w2x2 > x1r[j]) & (x2r[j] > w2x1)
                                  & (w2y2 > y1r[j]) & (y2r[j] > w2y1);
                        h |= hit2 ? bit2 : 0u;
                    }
                    hm[j] |= h;
                }
            }
            int adv = take2 ? 2 : 1;
            mcnt += adv; did += adv;
        }
        if (did == 0) break;                           // all keys dead
        __syncthreads();                               // B2: batch arrays visible

        // ---- replay: full exact body on set bits, ascending batch order ----
        // divergent LDS reads (well-defined), R12-proven structure
        #pragma unroll
        for (int j = 0; j < CAP; ++j) {
            if (T * j < cnt) {
                u32 m = hm[j];
                while (m) {
                    int b = (int)__builtin_ctz(m);
                    m &= (m - 1);
                    float4 wb = batchbox[b];
                    u32   wst = batchstat[b];
                    float wx1 = wb.x, wy1 = wb.y, wx2 = wb.z, wy2 = wb.w;
                    float warea = __fmul_rn(__fsub_rn(wx2, wx1), __fsub_rn(wy2, wy1));
                    u64 kj = key[j];
                    float ix1   = fmaxf(wx1, x1r[j]);
                    float iy1   = fmaxf(wy1, y1r[j]);
                    float ix2   = fminf(wx2, x2r[j]);
                    float iy2   = fminf(wy2, y2r[j]);
                    float iw    = fmaxf(__fsub_rn(ix2, ix1), 0.0f);
                    float ih    = fmaxf(__fsub_rn(iy2, iy1), 0.0f);
                    float inter = __fmul_rn(iw, ih);
                    float denom = __fadd_rn(__fsub_rn(__fadd_rn(warea, ar[j]), inter), 1e-8f);
                    float iou   = inter / denom;                // IEEE div
                    float t2    = __fmul_rn(iou, iou);
                    float decay = expf(__fmul_rn(-2.0f, t2));   // exp(-iou^2/0.5)
                    float sc    = __uint_as_float((u32)(kj >> 32));
                    float ns    = __fmul_rn(sc, decay);
                    bool  app   = (kj != 0) && (inter > 0.0f);
                    u64   nk    = ((u64)__float_as_uint(ns) << 32) | (kj & 0xFFFFFFFFull);
                    u64   upd   = app ? ((ns >= SCORE_THR) ? nk : 0ull) : kj;
                    key[j] = ((u32)kj == wst) ? 0ull : upd;     // winner-zero (static unique)
                }
            }
        }
    }

    // ---- batched flush of staged winners (boxes recovered by rank) ----
    int mfin = (mcnt <= cnt) ? mcnt : cnt;             // clamp: insurance only
    if (use_lds) {
        __syncthreads();
        int fl = (mfin <= BOXCAP) ? mfin : BOXCAP;
        for (int m = tid; m < fl; m += T) {
            u64 w = okey_lds[m];
            okey[m] = w;
            obox[m] = box_lds[(int)(w & 0xFFFF)];
        }
    }
    if (tid == 0) WS_CNT(ws)[cls] = mfin;
}

// merge the two strictly-descending key lists by rank; pad the tail
__global__ void softnms_merge(void* __restrict__ ws, float* __restrict__ out) {
    int k = blockIdx.x * blockDim.x + threadIdx.x;   // 0..4095
    const u64*    keyA = WS_KEY(ws, 0);
    const u64*    keyB = WS_KEY(ws, 1);
    const float4* boxA = WS_BOX(ws, 0);
    const float4* boxB = WS_BOX(ws, 1);
    const int mA = WS_CNT(ws)[0];
    const int mB = WS_CNT(ws)[1];

    float* ob = out;
    float* os = out + N_BOXES * 4;
    float* ol = out + N_BOXES * 5;

    if (k < mA) {
        u64 x = keyA[k];
        int lo = 0, hi = mB;
        while (lo < hi) { int mid = (lo + hi) >> 1; if (keyB[mid] > x) lo = mid + 1; else hi = mid; }
        int pos = k + lo;
        float4 b = boxA[k];
        ob[pos * 4 + 0] = b.x; ob[pos * 4 + 1] = b.y;
        ob[pos * 4 + 2] = b.z; ob[pos * 4 + 3] = b.w;
        os[pos] = __uint_as_float((u32)(x >> 32));
        ol[pos] = 0.0f;
    } else if (k < mA + mB) {
        int i = k - mA;
        u64 x = keyB[i];
        int lo = 0, hi = mA;
        while (lo < hi) { int mid = (lo + hi) >> 1; if (keyA[mid] > x) lo = mid + 1; else hi = mid; }
        int pos = i + lo;
        float4 b = boxB[i];
        ob[pos * 4 + 0] = b.x; ob[pos * 4 + 1] = b.y;
        ob[pos * 4 + 2] = b.z; ob[pos * 4 + 3] = b.w;
        os[pos] = __uint_as_float((u32)(x >> 32));
        ol[pos] = 1.0f;
    } else {
        ob[k * 4 + 0] = 0.0f; ob[k * 4 + 1] = 0.0f;
        ob[k * 4 + 2] = 0.0f; ob[k * 4 + 3] = 0.0f;
        os[k] = 0.0f;
        ol[k] = -1.0f;
    }
}

extern "C" void kernel_launch(void* const* d_in, const int* in_sizes, int n_in,
                              void* d_out, int out_size, void* d_ws, size_t ws_size,
                              hipStream_t stream) {
    const float* boxes  = (const float*)d_in[0];
    const float* scores = (const float*)d_in[1];
    const int*   labels = (const int*)d_in[2];
    float* out = (float*)d_out;
    (void)in_sizes; (void)n_in; (void)out_size; (void)ws_size;
    softnms_fused<<<2, T, 0, stream>>>(boxes, scores, labels, d_ws);
    softnms_merge<<<N_BOXES / 256, 256, 0, stream>>>(d_ws, out);
}